// Round 6
// baseline (528.158 us; speedup 1.0000x reference)
//
#include <hip/hip_runtime.h>
#include <hip/hip_bf16.h>

#define N_NODES 50000
#define N_EDGES 250000
#define NHEAD   12
#define NH      (N_NODES * NHEAD)   /* 600000 rows of 64 */
#define ROW_TILES (NH / 16)         /* 37500 */

typedef __bf16 bf16_t;
typedef __bf16 bf16x8 __attribute__((ext_vector_type(8)));
typedef __bf16 bf16x4 __attribute__((ext_vector_type(4)));
typedef float  f32x4  __attribute__((ext_vector_type(4)));

__device__ __forceinline__ bf16x8 cvt8(f32x4 a, f32x4 b) {
    bf16x8 r;
    r[0] = (bf16_t)a[0]; r[1] = (bf16_t)a[1]; r[2] = (bf16_t)a[2]; r[3] = (bf16_t)a[3];
    r[4] = (bf16_t)b[0]; r[5] = (bf16_t)b[1]; r[6] = (bf16_t)b[2]; r[7] = (bf16_t)b[3];
    return r;
}

// ---------------- degree histogram + weight bf16 pre-conversion ----------------
__global__ __launch_bounds__(256) void k_deg_prep(
    const int* __restrict__ dst, int* __restrict__ deg,
    const float* __restrict__ wfc, const float* __restrict__ wres,
    bf16_t* __restrict__ wfb, bf16_t* __restrict__ wrb)
{
    int b = blockIdx.x;
    if (b < 977) {
        int i = b * 256 + threadIdx.x;
        if (i < N_EDGES) atomicAdd(&deg[dst[i]], 1);
    } else {
        int t = (b - 977) * 256 + threadIdx.x;   // 0..4095
        wfb[t] = (bf16_t)wfc[t];
        wrb[t] = (bf16_t)wres[t];
    }
}

// single block, 1024 threads, 52 nodes/thread; int4-vectorized loads.
__global__ __launch_bounds__(1024) void k_scan(const int* __restrict__ deg,
                                               int* __restrict__ rowptr,
                                               int* __restrict__ cursor) {
    __shared__ int s[1024];
    const int CH = 52;
    int t = threadIdx.x;
    int base = t * CH;
    int loc[CH];
    if (base + CH <= N_NODES) {
        const int4* p = reinterpret_cast<const int4*>(deg + base);
#pragma unroll
        for (int i = 0; i < CH / 4; ++i) {
            int4 q = p[i];
            loc[4 * i + 0] = q.x; loc[4 * i + 1] = q.y;
            loc[4 * i + 2] = q.z; loc[4 * i + 3] = q.w;
        }
    } else {
#pragma unroll
        for (int i = 0; i < CH; ++i) {
            int idx = base + i;
            loc[i] = (idx < N_NODES) ? deg[idx] : 0;
        }
    }
    int sum = 0;
#pragma unroll
    for (int i = 0; i < CH; ++i) sum += loc[i];
    s[t] = sum;
    __syncthreads();
    for (int off = 1; off < 1024; off <<= 1) {
        int v = (t >= off) ? s[t - off] : 0;
        __syncthreads();
        s[t] += v;
        __syncthreads();
    }
    int run = s[t] - sum;
#pragma unroll
    for (int i = 0; i < CH; ++i) {
        int idx = base + i;
        if (idx < N_NODES) {
            rowptr[idx] = run;
            cursor[idx] = run;
            run += loc[i];
        }
    }
    if (t == 1023) rowptr[N_NODES] = s[1023];
}

// CSR fill; also records csrdst so k_edgew is CSR-ordered.
__global__ __launch_bounds__(256) void k_fill(const int* __restrict__ src,
                                              const int* __restrict__ dst,
                                              int* __restrict__ cursor,
                                              int* __restrict__ csr_src,
                                              int* __restrict__ csr_dst) {
    int i = blockIdx.x * 256 + threadIdx.x;
    if (i < N_EDGES) {
        int d = dst[i];
        int pos = atomicAdd(&cursor[d], 1);
        csr_src[pos] = src[i];
        csr_dst[pos] = d;
    }
}

// ---------------- GEMM: ft = X*Wfc^T, res = X*Wres^T (swapped-operand MFMA) ----------------
__global__ __launch_bounds__(256) void k_gemm(
    const float* __restrict__ h,
    const bf16_t* __restrict__ wfb,
    const bf16_t* __restrict__ wrb,
    const float* __restrict__ attl,
    const float* __restrict__ attr,
    bf16_t* __restrict__ ft,
    bf16_t* __restrict__ resb,
    float* __restrict__ al,
    float* __restrict__ ar)
{
    int wid  = (blockIdx.x * blockDim.x + threadIdx.x) >> 6;
    if (wid >= ROW_TILES) return;
    int lane = threadIdx.x & 63;
    int lr = lane & 15, lg = lane >> 4;
    int r0 = wid << 4;

    const f32x4*  hv = reinterpret_cast<const f32x4*>(h);
    const bf16x8* wf = reinterpret_cast<const bf16x8*>(wfb);
    const bf16x8* wr = reinterpret_cast<const bf16x8*>(wrb);

    int abase = (r0 + lr) * 16 + lg * 2;              // f32x4 units
    bf16x8 a0 = cvt8(hv[abase + 0], hv[abase + 1]);
    bf16x8 a1 = cvt8(hv[abase + 8], hv[abase + 9]);

    f32x4 dfc[4], dre[4];
#pragma unroll
    for (int nt = 0; nt < 4; ++nt) {
        int brow = (nt * 16 + lr) * 8;                // bf16x8 units per 64-elem row
        f32x4 z = {0.f, 0.f, 0.f, 0.f};
        z = __builtin_amdgcn_mfma_f32_16x16x32_bf16(wf[brow + lg],     a0, z, 0, 0, 0);
        z = __builtin_amdgcn_mfma_f32_16x16x32_bf16(wf[brow + 4 + lg], a1, z, 0, 0, 0);
        dfc[nt] = z;
        f32x4 y = {0.f, 0.f, 0.f, 0.f};
        y = __builtin_amdgcn_mfma_f32_16x16x32_bf16(wr[brow + lg],     a0, y, 0, 0, 0);
        y = __builtin_amdgcn_mfma_f32_16x16x32_bf16(wr[brow + 4 + lg], a1, y, 0, 0, 0);
        dre[nt] = y;
    }

    int r  = r0 + lr;           // this lane's node row
    int hh = r % NHEAD;
    float pl = 0.f, pr = 0.f;
#pragma unroll
    for (int nt = 0; nt < 4; ++nt) {
        bf16x4 pf, pe;
#pragma unroll
        for (int j = 0; j < 4; ++j) {
            int c = nt * 16 + lg * 4 + j;
            float vf = dfc[nt][j];
            pl += vf * attl[hh * 64 + c];
            pr += vf * attr[hh * 64 + c];
            pf[j] = (bf16_t)vf;
            pe[j] = (bf16_t)dre[nt][j];
        }
        *reinterpret_cast<bf16x4*>(ft   + r * 64 + nt * 16 + lg * 4) = pf;
        *reinterpret_cast<bf16x4*>(resb + r * 64 + nt * 16 + lg * 4) = pe;
    }
    pl += __shfl_xor(pl, 16); pl += __shfl_xor(pl, 32);
    pr += __shfl_xor(pr, 16); pr += __shfl_xor(pr, 32);
    if (lane < 16) {
        al[r0 + lane] = pl;
        ar[r0 + lane] = pr;
    }
}

// ---------------- per-edge softmax weights, all 12 heads, CSR order ----------------
__global__ __launch_bounds__(256) void k_edgew(
    const int* __restrict__ csr_src, const int* __restrict__ csr_dst,
    const float* __restrict__ al, const float* __restrict__ ar,
    float* __restrict__ w)
{
    int e = blockIdx.x * 256 + threadIdx.x;
    if (e >= N_EDGES) return;
    int s = csr_src[e], d = csr_dst[e];
    const f32x4* ap = reinterpret_cast<const f32x4*>(al + s * NHEAD);
    const f32x4* bp = reinterpret_cast<const f32x4*>(ar + d * NHEAD);
#pragma unroll
    for (int q = 0; q < 3; ++q) {
        f32x4 a = ap[q], b = bp[q];
#pragma unroll
        for (int j = 0; j < 4; ++j) {
            float x = a[j] + b[j];
            x = (x > 0.f) ? x : 0.2f * x;          // leaky_relu
            w[(q * 4 + j) * N_EDGES + e] = __expf(x);
        }
    }
}

// ---------------- softmax-normalize + aggregate + residual + relu ----------------
// HEAD-MAJOR wave order: wid = hh*N_NODES + d0. All dsts of head h run as one
// temporal phase -> the active ft gather slice is 6.4MB and each unique line's
// ~5 reuses (out-degree) cluster in time -> repeat requests hit L2/L3 instead
// of consuming line-fill-path slots (the measured ~13 G lines/s wall).
#define DB 8
__global__ __launch_bounds__(256) void k_agg(
    const int* __restrict__ rowptr, const int* __restrict__ csr_src,
    const float* __restrict__ w,
    const bf16_t* __restrict__ ft, const bf16_t* __restrict__ resb,
    float* __restrict__ out)
{
    int wid = (blockIdx.x * 256 + threadIdx.x) >> 6;
    if (wid >= NH) return;
    int lane = threadIdx.x & 63;
    int hh = wid / N_NODES;          // head-major
    int d0 = wid - hh * N_NODES;
    int row = d0 * NHEAD + hh;
    int beg = rowptr[d0], end = rowptr[d0 + 1];
    float r = (float)__builtin_nontemporal_load(&resb[row * 64 + lane]);
    const float* wrow = w + hh * N_EDGES;
    float acc = 0.f, den = 0.f;
    for (int j0 = beg; j0 < end; j0 += DB) {
        int idx[DB]; float wv[DB], v[DB];
#pragma unroll
        for (int u = 0; u < DB; ++u) {
            int j = j0 + u;
            idx[u] = (j < end) ? csr_src[j] : -1;
        }
#pragma unroll
        for (int u = 0; u < DB; ++u)
            wv[u] = (idx[u] >= 0) ? __builtin_nontemporal_load(&wrow[j0 + u]) : 0.f;
#pragma unroll
        for (int u = 0; u < DB; ++u)
            v[u] = (idx[u] >= 0) ? (float)ft[idx[u] * 768 + hh * 64 + lane] : 0.f;
#pragma unroll
        for (int u = 0; u < DB; ++u) { den += wv[u]; acc += wv[u] * v[u]; }
    }
    float o = r + acc / den;
    __builtin_nontemporal_store(o > 0.f ? o : 0.f, &out[row * 64 + lane]);
}

extern "C" void kernel_launch(void* const* d_in, const int* in_sizes, int n_in,
                              void* d_out, int out_size, void* d_ws, size_t ws_size,
                              hipStream_t stream) {
    const float* h    = (const float*)d_in[0];
    const float* wfc  = (const float*)d_in[1];
    const float* attl = (const float*)d_in[2];
    const float* attr = (const float*)d_in[3];
    const float* wres = (const float*)d_in[4];
    const int*   src  = (const int*)d_in[5];
    const int*   dst  = (const int*)d_in[6];
    float* out = (float*)d_out;

    char* ws = (char*)d_ws;
    bf16_t* ft     = (bf16_t*)(ws + 0);          //  76,800,000 B
    bf16_t* resb   = (bf16_t*)(ws + 76800000);   //  76,800,000 B
    float*  al     = (float*)(ws + 153600000);   //   2,400,000 B
    float*  ar     = (float*)(ws + 156000000);   //   2,400,000 B
    int*    deg    = (int*)(ws + 158400000);     //     200,448 B
    int*    rowptr = (int*)(ws + 158600448);     //     200,448 B
    int*    cursor = (int*)(ws + 158800896);     //     200,448 B
    int*    csrsrc = (int*)(ws + 159001344);     //   1,000,000 B
    int*    csrdst = (int*)(ws + 160001344);     //   1,000,000 B
    bf16_t* wfb    = (bf16_t*)(ws + 161001344);  //       8,192 B
    bf16_t* wrb    = (bf16_t*)(ws + 161009536);  //       8,192 B
    float*  wbuf   = (float*)(ws + 161017728);   //  12,000,000 B (end ~173 MB)

    hipMemsetAsync(deg, 0, N_NODES * sizeof(int), stream);
    k_deg_prep<<<993, 256, 0, stream>>>(dst, deg, wfc, wres, wfb, wrb);
    k_scan<<<1, 1024, 0, stream>>>(deg, rowptr, cursor);
    k_fill<<<977, 256, 0, stream>>>(src, dst, cursor, csrsrc, csrdst);
    k_gemm<<<ROW_TILES / 4, 256, 0, stream>>>(h, wfb, wrb, attl, attr, ft, resb, al, ar);
    k_edgew<<<977, 256, 0, stream>>>(csrsrc, csrdst, al, ar, wbuf);
    k_agg<<<NH / 4, 256, 0, stream>>>(rowptr, csrsrc, wbuf, ft, resb, out);
}

// Round 7
// 333.784 us; speedup vs baseline: 1.5823x; 1.5823x over previous
//
#include <hip/hip_runtime.h>
#include <hip/hip_bf16.h>

#define N_NODES 50000
#define N_EDGES 250000
#define NHEAD   12
#define NH      (N_NODES * NHEAD)   /* 600000 rows of 64 */
#define ROW_TILES (NH / 16)         /* 37500 */

typedef __bf16 bf16_t;
typedef __bf16 bf16x8 __attribute__((ext_vector_type(8)));
typedef __bf16 bf16x4 __attribute__((ext_vector_type(4)));
typedef float  f32x4  __attribute__((ext_vector_type(4)));

__device__ __forceinline__ bf16x8 cvt8(f32x4 a, f32x4 b) {
    bf16x8 r;
    r[0] = (bf16_t)a[0]; r[1] = (bf16_t)a[1]; r[2] = (bf16_t)a[2]; r[3] = (bf16_t)a[3];
    r[4] = (bf16_t)b[0]; r[5] = (bf16_t)b[1]; r[6] = (bf16_t)b[2]; r[7] = (bf16_t)b[3];
    return r;
}

// ---------------- degree histogram + weight bf16 pre-conversion ----------------
__global__ __launch_bounds__(256) void k_deg_prep(
    const int* __restrict__ dst, int* __restrict__ deg,
    const float* __restrict__ wfc, const float* __restrict__ wres,
    bf16_t* __restrict__ wfb, bf16_t* __restrict__ wrb)
{
    int b = blockIdx.x;
    if (b < 977) {
        int i = b * 256 + threadIdx.x;
        if (i < N_EDGES) atomicAdd(&deg[dst[i]], 1);
    } else {
        int t = (b - 977) * 256 + threadIdx.x;   // 0..4095
        wfb[t] = (bf16_t)wfc[t];
        wrb[t] = (bf16_t)wres[t];
    }
}

// single block, 1024 threads, 52 nodes/thread; int4-vectorized loads.
__global__ __launch_bounds__(1024) void k_scan(const int* __restrict__ deg,
                                               int* __restrict__ rowptr,
                                               int* __restrict__ cursor) {
    __shared__ int s[1024];
    const int CH = 52;
    int t = threadIdx.x;
    int base = t * CH;
    int loc[CH];
    if (base + CH <= N_NODES) {
        const int4* p = reinterpret_cast<const int4*>(deg + base);
#pragma unroll
        for (int i = 0; i < CH / 4; ++i) {
            int4 q = p[i];
            loc[4 * i + 0] = q.x; loc[4 * i + 1] = q.y;
            loc[4 * i + 2] = q.z; loc[4 * i + 3] = q.w;
        }
    } else {
#pragma unroll
        for (int i = 0; i < CH; ++i) {
            int idx = base + i;
            loc[i] = (idx < N_NODES) ? deg[idx] : 0;
        }
    }
    int sum = 0;
#pragma unroll
    for (int i = 0; i < CH; ++i) sum += loc[i];
    s[t] = sum;
    __syncthreads();
    for (int off = 1; off < 1024; off <<= 1) {
        int v = (t >= off) ? s[t - off] : 0;
        __syncthreads();
        s[t] += v;
        __syncthreads();
    }
    int run = s[t] - sum;
#pragma unroll
    for (int i = 0; i < CH; ++i) {
        int idx = base + i;
        if (idx < N_NODES) {
            rowptr[idx] = run;
            cursor[idx] = run;
            run += loc[i];
        }
    }
    if (t == 1023) rowptr[N_NODES] = s[1023];
}

// CSR fill; also records csrdst so k_edgew is CSR-ordered.
__global__ __launch_bounds__(256) void k_fill(const int* __restrict__ src,
                                              const int* __restrict__ dst,
                                              int* __restrict__ cursor,
                                              int* __restrict__ csr_src,
                                              int* __restrict__ csr_dst) {
    int i = blockIdx.x * 256 + threadIdx.x;
    if (i < N_EDGES) {
        int d = dst[i];
        int pos = atomicAdd(&cursor[d], 1);
        csr_src[pos] = src[i];
        csr_dst[pos] = d;
    }
}

// ---------------- GEMM: ft = X*Wfc^T, res = X*Wres^T (swapped-operand MFMA) ----------------
__global__ __launch_bounds__(256) void k_gemm(
    const float* __restrict__ h,
    const bf16_t* __restrict__ wfb,
    const bf16_t* __restrict__ wrb,
    const float* __restrict__ attl,
    const float* __restrict__ attr,
    bf16_t* __restrict__ ft,
    bf16_t* __restrict__ resb,
    float* __restrict__ al,
    float* __restrict__ ar)
{
    int wid  = (blockIdx.x * blockDim.x + threadIdx.x) >> 6;
    if (wid >= ROW_TILES) return;
    int lane = threadIdx.x & 63;
    int lr = lane & 15, lg = lane >> 4;
    int r0 = wid << 4;

    const f32x4*  hv = reinterpret_cast<const f32x4*>(h);
    const bf16x8* wf = reinterpret_cast<const bf16x8*>(wfb);
    const bf16x8* wr = reinterpret_cast<const bf16x8*>(wrb);

    int abase = (r0 + lr) * 16 + lg * 2;              // f32x4 units
    bf16x8 a0 = cvt8(hv[abase + 0], hv[abase + 1]);
    bf16x8 a1 = cvt8(hv[abase + 8], hv[abase + 9]);

    f32x4 dfc[4], dre[4];
#pragma unroll
    for (int nt = 0; nt < 4; ++nt) {
        int brow = (nt * 16 + lr) * 8;                // bf16x8 units per 64-elem row
        f32x4 z = {0.f, 0.f, 0.f, 0.f};
        z = __builtin_amdgcn_mfma_f32_16x16x32_bf16(wf[brow + lg],     a0, z, 0, 0, 0);
        z = __builtin_amdgcn_mfma_f32_16x16x32_bf16(wf[brow + 4 + lg], a1, z, 0, 0, 0);
        dfc[nt] = z;
        f32x4 y = {0.f, 0.f, 0.f, 0.f};
        y = __builtin_amdgcn_mfma_f32_16x16x32_bf16(wr[brow + lg],     a0, y, 0, 0, 0);
        y = __builtin_amdgcn_mfma_f32_16x16x32_bf16(wr[brow + 4 + lg], a1, y, 0, 0, 0);
        dre[nt] = y;
    }

    int r  = r0 + lr;           // this lane's node row
    int hh = r % NHEAD;
    float pl = 0.f, pr = 0.f;
#pragma unroll
    for (int nt = 0; nt < 4; ++nt) {
        bf16x4 pf, pe;
#pragma unroll
        for (int j = 0; j < 4; ++j) {
            int c = nt * 16 + lg * 4 + j;
            float vf = dfc[nt][j];
            pl += vf * attl[hh * 64 + c];
            pr += vf * attr[hh * 64 + c];
            pf[j] = (bf16_t)vf;
            pe[j] = (bf16_t)dre[nt][j];
        }
        *reinterpret_cast<bf16x4*>(ft   + r * 64 + nt * 16 + lg * 4) = pf;
        *reinterpret_cast<bf16x4*>(resb + r * 64 + nt * 16 + lg * 4) = pe;
    }
    pl += __shfl_xor(pl, 16); pl += __shfl_xor(pl, 32);
    pr += __shfl_xor(pr, 16); pr += __shfl_xor(pr, 32);
    if (lane < 16) {
        al[r0 + lane] = pl;
        ar[r0 + lane] = pr;
    }
}

// ---------------- per-edge softmax weights, all 12 heads, EDGE-major [E][12] ----------------
// Thread = one CSR edge position. al gather is a random 48B touch on a 2.4MB
// L2-resident table; ar reads are sequential (csr is dst-sorted). Output
// w[e*12+h]: 48B contiguous per thread, 3KB per wave, 16B-aligned (48|16).
__global__ __launch_bounds__(256) void k_edgew(
    const int* __restrict__ csr_src, const int* __restrict__ csr_dst,
    const float* __restrict__ al, const float* __restrict__ ar,
    float* __restrict__ w)
{
    int e = blockIdx.x * 256 + threadIdx.x;
    if (e >= N_EDGES) return;
    int s = csr_src[e], d = csr_dst[e];
    const f32x4* ap = reinterpret_cast<const f32x4*>(al + s * NHEAD);
    const f32x4* bp = reinterpret_cast<const f32x4*>(ar + d * NHEAD);
    f32x4* wp = reinterpret_cast<f32x4*>(w + e * NHEAD);
#pragma unroll
    for (int q = 0; q < 3; ++q) {
        f32x4 a = ap[q], b = bp[q];
        f32x4 o;
#pragma unroll
        for (int j = 0; j < 4; ++j) {
            float x = a[j] + b[j];
            x = (x > 0.f) ? x : 0.2f * x;          // leaky_relu
            o[j] = __expf(x);
        }
        wp[q] = o;
    }
}

// ---------------- softmax-normalize + aggregate + residual + relu ----------------
// ONE WAVE PER DST NODE, all 12 heads at once. Per edge the wave reads the full
// contiguous 1536B ft row as TWO requests (dwordx4 + dwordx2) instead of twelve
// 128B requests from unrelated waves -> ~4x fewer VMEM requests through the
// measured ~13G req/s service wall, and ideal DRAM page locality.
// Lane l owns: part A = head l>>3, feats (l&7)*8..+7  (row elems 8l..8l+7)
//             part B = head 8+(l>>4), feats (l&15)*4..+3 (elems 512+4l..+3)
// Head weights are wave-broadcast scalar loads from the sequential w[E][12].
#define DB 4
__global__ __launch_bounds__(256) void k_agg(
    const int* __restrict__ rowptr, const int* __restrict__ csr_src,
    const float* __restrict__ w,
    const bf16_t* __restrict__ ft, const bf16_t* __restrict__ resb,
    float* __restrict__ out)
{
    int d0 = (blockIdx.x * 256 + threadIdx.x) >> 6;
    if (d0 >= N_NODES) return;
    int l  = threadIdx.x & 63;
    int hA = l >> 3;
    int hB = 8 + (l >> 4);
    int beg = rowptr[d0], end = rowptr[d0 + 1];

    float accA[8] = {0,0,0,0,0,0,0,0};
    float accB[4] = {0,0,0,0};
    float denA = 0.f, denB = 0.f;

    for (int j0 = beg; j0 < end; j0 += DB) {
        int idx[DB]; float wA[DB], wB[DB];
        bf16x8 vA[DB]; bf16x4 vB[DB];
#pragma unroll
        for (int u = 0; u < DB; ++u) {
            int j = j0 + u;
            bool ok = j < end;                 // wave-uniform
            idx[u] = csr_src[ok ? j : beg];
            wA[u] = ok ? w[j * NHEAD + hA] : 0.f;
            wB[u] = ok ? w[j * NHEAD + hB] : 0.f;
        }
#pragma unroll
        for (int u = 0; u < DB; ++u) {
            const bf16_t* row = ft + idx[u] * 768;
            vA[u] = *reinterpret_cast<const bf16x8*>(row + 8 * l);
            vB[u] = *reinterpret_cast<const bf16x4*>(row + 512 + 4 * l);
        }
#pragma unroll
        for (int u = 0; u < DB; ++u) {
            denA += wA[u]; denB += wB[u];
#pragma unroll
            for (int k = 0; k < 8; ++k) accA[k] += wA[u] * (float)vA[u][k];
#pragma unroll
            for (int k = 0; k < 4; ++k) accB[k] += wB[u] * (float)vB[u][k];
        }
    }

    const bf16_t* rrow = resb + d0 * 768;
    bf16x8 rA = *reinterpret_cast<const bf16x8*>(rrow + 8 * l);
    bf16x4 rB = *reinterpret_cast<const bf16x4*>(rrow + 512 + 4 * l);
    float* orow = out + d0 * 768;
    f32x4 o0, o1, o2;
    float ia = 1.f / denA, ib = 1.f / denB;
#pragma unroll
    for (int k = 0; k < 4; ++k) {
        float x = (float)rA[k] + accA[k] * ia;         o0[k] = x > 0.f ? x : 0.f;
        float y = (float)rA[k + 4] + accA[k + 4] * ia; o1[k] = y > 0.f ? y : 0.f;
        float z = (float)rB[k] + accB[k] * ib;         o2[k] = z > 0.f ? z : 0.f;
    }
    __builtin_nontemporal_store(o0, reinterpret_cast<f32x4*>(orow + 8 * l));
    __builtin_nontemporal_store(o1, reinterpret_cast<f32x4*>(orow + 8 * l + 4));
    __builtin_nontemporal_store(o2, reinterpret_cast<f32x4*>(orow + 512 + 4 * l));
}

extern "C" void kernel_launch(void* const* d_in, const int* in_sizes, int n_in,
                              void* d_out, int out_size, void* d_ws, size_t ws_size,
                              hipStream_t stream) {
    const float* h    = (const float*)d_in[0];
    const float* wfc  = (const float*)d_in[1];
    const float* attl = (const float*)d_in[2];
    const float* attr = (const float*)d_in[3];
    const float* wres = (const float*)d_in[4];
    const int*   src  = (const int*)d_in[5];
    const int*   dst  = (const int*)d_in[6];
    float* out = (float*)d_out;

    char* ws = (char*)d_ws;
    bf16_t* ft     = (bf16_t*)(ws + 0);          //  76,800,000 B
    bf16_t* resb   = (bf16_t*)(ws + 76800000);   //  76,800,000 B
    float*  al     = (float*)(ws + 153600000);   //   2,400,000 B
    float*  ar     = (float*)(ws + 156000000);   //   2,400,000 B
    int*    deg    = (int*)(ws + 158400000);     //     200,448 B
    int*    rowptr = (int*)(ws + 158600448);     //     200,448 B
    int*    cursor = (int*)(ws + 158800896);     //     200,448 B
    int*    csrsrc = (int*)(ws + 159001344);     //   1,000,000 B
    int*    csrdst = (int*)(ws + 160001344);     //   1,000,000 B
    bf16_t* wfb    = (bf16_t*)(ws + 161001344);  //       8,192 B
    bf16_t* wrb    = (bf16_t*)(ws + 161009536);  //       8,192 B
    float*  wbuf   = (float*)(ws + 161017728);   //  12,000,000 B (end ~173 MB)

    hipMemsetAsync(deg, 0, N_NODES * sizeof(int), stream);
    k_deg_prep<<<993, 256, 0, stream>>>(dst, deg, wfc, wres, wfb, wrb);
    k_scan<<<1, 1024, 0, stream>>>(deg, rowptr, cursor);
    k_fill<<<977, 256, 0, stream>>>(src, dst, cursor, csrsrc, csrdst);
    k_gemm<<<ROW_TILES / 4, 256, 0, stream>>>(h, wfb, wrb, attl, attr, ft, resb, al, ar);
    k_edgew<<<977, 256, 0, stream>>>(csrsrc, csrdst, al, ar, wbuf);
    k_agg<<<(N_NODES + 3) / 4, 256, 0, stream>>>(rowptr, csrsrc, wbuf, ft, resb, out);
}

// Round 9
// 315.951 us; speedup vs baseline: 1.6716x; 1.0564x over previous
//
#include <hip/hip_runtime.h>
#include <hip/hip_bf16.h>

#define N_NODES 50000
#define N_EDGES 250000
#define NHEAD   12
#define NH      (N_NODES * NHEAD)   /* 600000 rows of 64 */
#define ROW_TILES (NH / 16)         /* 37500 */

typedef __bf16 bf16_t;
typedef __bf16 bf16x8 __attribute__((ext_vector_type(8)));
typedef __bf16 bf16x4 __attribute__((ext_vector_type(4)));
typedef float  f32x4  __attribute__((ext_vector_type(4)));

__device__ __forceinline__ bf16x8 cvt8(f32x4 a, f32x4 b) {
    bf16x8 r;
    r[0] = (bf16_t)a[0]; r[1] = (bf16_t)a[1]; r[2] = (bf16_t)a[2]; r[3] = (bf16_t)a[3];
    r[4] = (bf16_t)b[0]; r[5] = (bf16_t)b[1]; r[6] = (bf16_t)b[2]; r[7] = (bf16_t)b[3];
    return r;
}

// ---------------- prep: degree histogram, weight cvt, ul/ur = W^T.att tables ----------------
// b<977: edge-degree atomics; b<993: wfc/wres->bf16; b<997: ul; b<1001: ur.
// ul[h][d] = sum_e attl[h][e]*Wfc[e][d]  (so a1[row] = sum_d h[row,d]*ul[h,d]).
// ur[h][d] = sum_e attr[h][e]*Wfc[e][d]  (a2 is a dot with ft, which uses Wfc).
// Tables stored [16][64] bf16, rows 12..15 zeroed (MFMA pad).
__global__ __launch_bounds__(256) void k_deg_prep(
    const int* __restrict__ dst, int* __restrict__ deg,
    const float* __restrict__ wfc, const float* __restrict__ wres,
    const float* __restrict__ attl, const float* __restrict__ attr,
    bf16_t* __restrict__ wfb, bf16_t* __restrict__ wrb,
    bf16_t* __restrict__ ulb, bf16_t* __restrict__ urb)
{
    int b = blockIdx.x;
    if (b < 977) {
        int i = b * 256 + threadIdx.x;
        if (i < N_EDGES) atomicAdd(&deg[dst[i]], 1);
    } else if (b < 993) {
        int t = (b - 977) * 256 + threadIdx.x;   // 0..4095
        wfb[t] = (bf16_t)wfc[t];
        wrb[t] = (bf16_t)wres[t];
    } else if (b < 997) {
        int u = (b - 993) * 256 + threadIdx.x;   // 0..1023
        int hh = u >> 6, d = u & 63;
        float s = 0.f;
        if (hh < NHEAD) {
#pragma unroll 8
            for (int e = 0; e < 64; ++e) s += attl[hh * 64 + e] * wfc[e * 64 + d];
        }
        ulb[u] = (bf16_t)s;
    } else {
        int u = (b - 997) * 256 + threadIdx.x;   // 0..1023
        int hh = u >> 6, d = u & 63;
        float s = 0.f;
        if (hh < NHEAD) {
#pragma unroll 8
            for (int e = 0; e < 64; ++e) s += attr[hh * 64 + e] * wfc[e * 64 + d];
        }
        urb[u] = (bf16_t)s;
    }
}

// single block, 1024 threads, 52 nodes/thread; int4-vectorized loads.
__global__ __launch_bounds__(1024) void k_scan(const int* __restrict__ deg,
                                               int* __restrict__ rowptr,
                                               int* __restrict__ cursor) {
    __shared__ int s[1024];
    const int CH = 52;
    int t = threadIdx.x;
    int base = t * CH;
    int loc[CH];
    if (base + CH <= N_NODES) {
        const int4* p = reinterpret_cast<const int4*>(deg + base);
#pragma unroll
        for (int i = 0; i < CH / 4; ++i) {
            int4 q = p[i];
            loc[4 * i + 0] = q.x; loc[4 * i + 1] = q.y;
            loc[4 * i + 2] = q.z; loc[4 * i + 3] = q.w;
        }
    } else {
#pragma unroll
        for (int i = 0; i < CH; ++i) {
            int idx = base + i;
            loc[i] = (idx < N_NODES) ? deg[idx] : 0;
        }
    }
    int sum = 0;
#pragma unroll
    for (int i = 0; i < CH; ++i) sum += loc[i];
    s[t] = sum;
    __syncthreads();
    for (int off = 1; off < 1024; off <<= 1) {
        int v = (t >= off) ? s[t - off] : 0;
        __syncthreads();
        s[t] += v;
        __syncthreads();
    }
    int run = s[t] - sum;
#pragma unroll
    for (int i = 0; i < CH; ++i) {
        int idx = base + i;
        if (idx < N_NODES) {
            rowptr[idx] = run;
            cursor[idx] = run;
            run += loc[i];
        }
    }
    if (t == 1023) rowptr[N_NODES] = s[1023];
}

// CSR fill; also records csrdst so k_edgew is CSR-ordered.
__global__ __launch_bounds__(256) void k_fill(const int* __restrict__ src,
                                              const int* __restrict__ dst,
                                              int* __restrict__ cursor,
                                              int* __restrict__ csr_src,
                                              int* __restrict__ csr_dst) {
    int i = blockIdx.x * 256 + threadIdx.x;
    if (i < N_EDGES) {
        int d = dst[i];
        int pos = atomicAdd(&cursor[d], 1);
        csr_src[pos] = src[i];
        csr_dst[pos] = d;
    }
}

// ---------------- GEMM: ft = X*Wfc^T, res = X*Wres^T + MFMA attn dots ----------------
// 2 row-tiles per wave; all 8 A-loads issued up front (2x in-flight bytes).
// Main gemm: mfma(W_frag, h_frag) -> D col(lane&15)=node, regs=output cols.
// Attn dots: mfma(ul_frag, h_frag) -> D col=node, regs=heads; the lane group
// holding head r%12 writes al/ar[r]. No per-lane table gathers, no shuffles.
__global__ __launch_bounds__(256) void k_gemm(
    const float* __restrict__ h,
    const bf16_t* __restrict__ wfb,
    const bf16_t* __restrict__ wrb,
    const bf16_t* __restrict__ ulb,
    const bf16_t* __restrict__ urb,
    bf16_t* __restrict__ ft,
    bf16_t* __restrict__ resb,
    float* __restrict__ al,
    float* __restrict__ ar)
{
    int gwid = (blockIdx.x * blockDim.x + threadIdx.x) >> 6;
    int t0 = gwid * 2;
    if (t0 >= ROW_TILES) return;
    int lane = threadIdx.x & 63;
    int lr = lane & 15, lg = lane >> 4;
    bool v1 = (t0 + 1 < ROW_TILES);
    int tb1 = v1 ? t0 + 1 : t0;

    const f32x4* hv = reinterpret_cast<const f32x4*>(h);
    f32x4 raw[2][4];
    {
        int ab0 = (t0 * 16 + lr) * 16 + lg * 2;
        int ab1 = (tb1 * 16 + lr) * 16 + lg * 2;
        raw[0][0] = hv[ab0];     raw[0][1] = hv[ab0 + 1];
        raw[0][2] = hv[ab0 + 8]; raw[0][3] = hv[ab0 + 9];
        raw[1][0] = hv[ab1];     raw[1][1] = hv[ab1 + 1];
        raw[1][2] = hv[ab1 + 8]; raw[1][3] = hv[ab1 + 9];
    }
    const bf16x8* ulv = reinterpret_cast<const bf16x8*>(ulb);
    const bf16x8* urv = reinterpret_cast<const bf16x8*>(urb);
    bf16x8 ul0 = ulv[lr * 8 + lg], ul1 = ulv[lr * 8 + 4 + lg];
    bf16x8 ur0 = urv[lr * 8 + lg], ur1 = urv[lr * 8 + 4 + lg];
    const bf16x8* wf = reinterpret_cast<const bf16x8*>(wfb);
    const bf16x8* wr = reinterpret_cast<const bf16x8*>(wrb);

#pragma unroll
    for (int tt = 0; tt < 2; ++tt) {
        if (tt == 1 && !v1) break;
        int r0 = (tt ? tb1 : t0) << 4;
        bf16x8 a0 = cvt8(raw[tt][0], raw[tt][1]);
        bf16x8 a1 = cvt8(raw[tt][2], raw[tt][3]);

        // attn dots via MFMA: D[head][node]
        f32x4 dl = {0.f, 0.f, 0.f, 0.f}, dr_ = {0.f, 0.f, 0.f, 0.f};
        dl  = __builtin_amdgcn_mfma_f32_16x16x32_bf16(ul0, a0, dl, 0, 0, 0);
        dl  = __builtin_amdgcn_mfma_f32_16x16x32_bf16(ul1, a1, dl, 0, 0, 0);
        dr_ = __builtin_amdgcn_mfma_f32_16x16x32_bf16(ur0, a0, dr_, 0, 0, 0);
        dr_ = __builtin_amdgcn_mfma_f32_16x16x32_bf16(ur1, a1, dr_, 0, 0, 0);
        int r  = r0 + lr;
        int hh = r % NHEAD;
        if (lg == (hh >> 2)) {
            al[r] = dl[hh & 3];
            ar[r] = dr_[hh & 3];
        }

#pragma unroll
        for (int nt = 0; nt < 4; ++nt) {
            int brow = (nt * 16 + lr) * 8;
            f32x4 z = {0.f, 0.f, 0.f, 0.f};
            z = __builtin_amdgcn_mfma_f32_16x16x32_bf16(wf[brow + lg],     a0, z, 0, 0, 0);
            z = __builtin_amdgcn_mfma_f32_16x16x32_bf16(wf[brow + 4 + lg], a1, z, 0, 0, 0);
            f32x4 y = {0.f, 0.f, 0.f, 0.f};
            y = __builtin_amdgcn_mfma_f32_16x16x32_bf16(wr[brow + lg],     a0, y, 0, 0, 0);
            y = __builtin_amdgcn_mfma_f32_16x16x32_bf16(wr[brow + 4 + lg], a1, y, 0, 0, 0);
            bf16x4 pf, pe;
#pragma unroll
            for (int j = 0; j < 4; ++j) {
                pf[j] = (bf16_t)z[j];
                pe[j] = (bf16_t)y[j];
            }
            *reinterpret_cast<bf16x4*>(ft   + r * 64 + nt * 16 + lg * 4) = pf;
            *reinterpret_cast<bf16x4*>(resb + r * 64 + nt * 16 + lg * 4) = pe;
        }
    }
}

// ---------------- per-edge softmax weights, all 12 heads, EDGE-major [E][12] ----------------
__global__ __launch_bounds__(256) void k_edgew(
    const int* __restrict__ csr_src, const int* __restrict__ csr_dst,
    const float* __restrict__ al, const float* __restrict__ ar,
    float* __restrict__ w)
{
    int e = blockIdx.x * 256 + threadIdx.x;
    if (e >= N_EDGES) return;
    int s = csr_src[e], d = csr_dst[e];
    const f32x4* ap = reinterpret_cast<const f32x4*>(al + s * NHEAD);
    const f32x4* bp = reinterpret_cast<const f32x4*>(ar + d * NHEAD);
    f32x4* wp = reinterpret_cast<f32x4*>(w + e * NHEAD);
#pragma unroll
    for (int q = 0; q < 3; ++q) {
        f32x4 a = ap[q], b = bp[q];
        f32x4 o;
#pragma unroll
        for (int j = 0; j < 4; ++j) {
            float x = a[j] + b[j];
            x = (x > 0.f) ? x : 0.2f * x;          // leaky_relu
            o[j] = __expf(x);
        }
        wp[q] = o;
    }
}

// ---------------- softmax-normalize + aggregate + residual + relu ----------------
// ONE WAVE PER DST NODE, all 12 heads; per edge two fat requests (1024B+512B).
#define DB 4
__global__ __launch_bounds__(256) void k_agg(
    const int* __restrict__ rowptr, const int* __restrict__ csr_src,
    const float* __restrict__ w,
    const bf16_t* __restrict__ ft, const bf16_t* __restrict__ resb,
    float* __restrict__ out)
{
    int d0 = (blockIdx.x * 256 + threadIdx.x) >> 6;
    if (d0 >= N_NODES) return;
    int l  = threadIdx.x & 63;
    int hA = l >> 3;
    int hB = 8 + (l >> 4);
    int beg = rowptr[d0], end = rowptr[d0 + 1];

    float accA[8] = {0,0,0,0,0,0,0,0};
    float accB[4] = {0,0,0,0};
    float denA = 0.f, denB = 0.f;

    for (int j0 = beg; j0 < end; j0 += DB) {
        int idx[DB]; float wA[DB], wB[DB];
        bf16x8 vA[DB]; bf16x4 vB[DB];
#pragma unroll
        for (int u = 0; u < DB; ++u) {
            int j = j0 + u;
            bool ok = j < end;                 // wave-uniform
            idx[u] = csr_src[ok ? j : beg];
            wA[u] = ok ? w[j * NHEAD + hA] : 0.f;
            wB[u] = ok ? w[j * NHEAD + hB] : 0.f;
        }
#pragma unroll
        for (int u = 0; u < DB; ++u) {
            const bf16_t* row = ft + idx[u] * 768;
            vA[u] = *reinterpret_cast<const bf16x8*>(row + 8 * l);
            vB[u] = *reinterpret_cast<const bf16x4*>(row + 512 + 4 * l);
        }
#pragma unroll
        for (int u = 0; u < DB; ++u) {
            denA += wA[u]; denB += wB[u];
#pragma unroll
            for (int k = 0; k < 8; ++k) accA[k] += wA[u] * (float)vA[u][k];
#pragma unroll
            for (int k = 0; k < 4; ++k) accB[k] += wB[u] * (float)vB[u][k];
        }
    }

    const bf16_t* rrow = resb + d0 * 768;
    bf16x8 rA = *reinterpret_cast<const bf16x8*>(rrow + 8 * l);
    bf16x4 rB = *reinterpret_cast<const bf16x4*>(rrow + 512 + 4 * l);
    float* orow = out + d0 * 768;
    f32x4 o0, o1, o2;
    float ia = 1.f / denA, ib = 1.f / denB;
#pragma unroll
    for (int k = 0; k < 4; ++k) {
        float x = (float)rA[k] + accA[k] * ia;         o0[k] = x > 0.f ? x : 0.f;
        float y = (float)rA[k + 4] + accA[k + 4] * ia; o1[k] = y > 0.f ? y : 0.f;
        float z = (float)rB[k] + accB[k] * ib;         o2[k] = z > 0.f ? z : 0.f;
    }
    __builtin_nontemporal_store(o0, reinterpret_cast<f32x4*>(orow + 8 * l));
    __builtin_nontemporal_store(o1, reinterpret_cast<f32x4*>(orow + 8 * l + 4));
    __builtin_nontemporal_store(o2, reinterpret_cast<f32x4*>(orow + 512 + 4 * l));
}

extern "C" void kernel_launch(void* const* d_in, const int* in_sizes, int n_in,
                              void* d_out, int out_size, void* d_ws, size_t ws_size,
                              hipStream_t stream) {
    const float* h    = (const float*)d_in[0];
    const float* wfc  = (const float*)d_in[1];
    const float* attl = (const float*)d_in[2];
    const float* attr = (const float*)d_in[3];
    const float* wres = (const float*)d_in[4];
    const int*   src  = (const int*)d_in[5];
    const int*   dst  = (const int*)d_in[6];
    float* out = (float*)d_out;

    char* ws = (char*)d_ws;
    bf16_t* ft     = (bf16_t*)(ws + 0);          //  76,800,000 B
    bf16_t* resb   = (bf16_t*)(ws + 76800000);   //  76,800,000 B
    float*  al     = (float*)(ws + 153600000);   //   2,400,000 B
    float*  ar     = (float*)(ws + 156000000);   //   2,400,000 B
    int*    deg    = (int*)(ws + 158400000);     //     200,448 B
    int*    rowptr = (int*)(ws + 158600448);     //     200,448 B
    int*    cursor = (int*)(ws + 158800896);     //     200,448 B
    int*    csrsrc = (int*)(ws + 159001344);     //   1,000,000 B
    int*    csrdst = (int*)(ws + 160001344);     //   1,000,000 B
    bf16_t* wfb    = (bf16_t*)(ws + 161001344);  //       8,192 B
    bf16_t* wrb    = (bf16_t*)(ws + 161009536);  //       8,192 B
    float*  wbuf   = (float*)(ws + 161017728);   //  12,000,000 B
    bf16_t* ulb    = (bf16_t*)(ws + 173017728);  //       2,048 B
    bf16_t* urb    = (bf16_t*)(ws + 173019776);  //       2,048 B (end ~173.02 MB)

    (void)hipMemsetAsync(deg, 0, N_NODES * sizeof(int), stream);
    k_deg_prep<<<1001, 256, 0, stream>>>(dst, deg, wfc, wres, attl, attr, wfb, wrb, ulb, urb);
    k_scan<<<1, 1024, 0, stream>>>(deg, rowptr, cursor);
    k_fill<<<977, 256, 0, stream>>>(src, dst, cursor, csrsrc, csrdst);
    k_gemm<<<(ROW_TILES / 2 + 3) / 4, 256, 0, stream>>>(h, wfb, wrb, ulb, urb, ft, resb, al, ar);
    k_edgew<<<977, 256, 0, stream>>>(csrsrc, csrdst, al, ar, wbuf);
    k_agg<<<(N_NODES + 3) / 4, 256, 0, stream>>>(rowptr, csrsrc, wbuf, ft, resb, out);
}

// Round 10
// 249.044 us; speedup vs baseline: 2.1207x; 1.2687x over previous
//
#include <hip/hip_runtime.h>
#include <hip/hip_bf16.h>

#define N_NODES 50000
#define N_EDGES 250000
#define NHEAD   12
#define NH      (N_NODES * NHEAD)   /* 600000 rows of 64 */
#define ROW_TILES (NH / 16)         /* 37500 */

typedef __bf16 bf16_t;
typedef __bf16 bf16x8 __attribute__((ext_vector_type(8)));
typedef __bf16 bf16x4 __attribute__((ext_vector_type(4)));
typedef float  f32x4  __attribute__((ext_vector_type(4)));

__device__ __forceinline__ bf16x8 cvt8(f32x4 a, f32x4 b) {
    bf16x8 r;
    r[0] = (bf16_t)a[0]; r[1] = (bf16_t)a[1]; r[2] = (bf16_t)a[2]; r[3] = (bf16_t)a[3];
    r[4] = (bf16_t)b[0]; r[5] = (bf16_t)b[1]; r[6] = (bf16_t)b[2]; r[7] = (bf16_t)b[3];
    return r;
}

// ---------------- prep: degree histogram, weight cvt, ul/ur = W^T.att tables ----------------
// ul[h][d] = sum_e attl[h][e]*Wfc[e][d]; ur[h][d] = sum_e attr[h][e]*Wfc[e][d].
// Tables stored [16][64] bf16, rows 12..15 zeroed (MFMA pad).
__global__ __launch_bounds__(256) void k_deg_prep(
    const int* __restrict__ dst, int* __restrict__ deg,
    const float* __restrict__ wfc, const float* __restrict__ wres,
    const float* __restrict__ attl, const float* __restrict__ attr,
    bf16_t* __restrict__ wfb, bf16_t* __restrict__ wrb,
    bf16_t* __restrict__ ulb, bf16_t* __restrict__ urb)
{
    int b = blockIdx.x;
    if (b < 977) {
        int i = b * 256 + threadIdx.x;
        if (i < N_EDGES) atomicAdd(&deg[dst[i]], 1);
    } else if (b < 993) {
        int t = (b - 977) * 256 + threadIdx.x;   // 0..4095
        wfb[t] = (bf16_t)wfc[t];
        wrb[t] = (bf16_t)wres[t];
    } else if (b < 997) {
        int u = (b - 993) * 256 + threadIdx.x;   // 0..1023
        int hh = u >> 6, d = u & 63;
        float s = 0.f;
        if (hh < NHEAD) {
#pragma unroll 8
            for (int e = 0; e < 64; ++e) s += attl[hh * 64 + e] * wfc[e * 64 + d];
        }
        ulb[u] = (bf16_t)s;
    } else {
        int u = (b - 997) * 256 + threadIdx.x;   // 0..1023
        int hh = u >> 6, d = u & 63;
        float s = 0.f;
        if (hh < NHEAD) {
#pragma unroll 8
            for (int e = 0; e < 64; ++e) s += attr[hh * 64 + e] * wfc[e * 64 + d];
        }
        urb[u] = (bf16_t)s;
    }
}

// single block, 1024 threads, 52 nodes/thread; int4-vectorized loads.
__global__ __launch_bounds__(1024) void k_scan(const int* __restrict__ deg,
                                               int* __restrict__ rowptr,
                                               int* __restrict__ cursor) {
    __shared__ int s[1024];
    const int CH = 52;
    int t = threadIdx.x;
    int base = t * CH;
    int loc[CH];
    if (base + CH <= N_NODES) {
        const int4* p = reinterpret_cast<const int4*>(deg + base);
#pragma unroll
        for (int i = 0; i < CH / 4; ++i) {
            int4 q = p[i];
            loc[4 * i + 0] = q.x; loc[4 * i + 1] = q.y;
            loc[4 * i + 2] = q.z; loc[4 * i + 3] = q.w;
        }
    } else {
#pragma unroll
        for (int i = 0; i < CH; ++i) {
            int idx = base + i;
            loc[i] = (idx < N_NODES) ? deg[idx] : 0;
        }
    }
    int sum = 0;
#pragma unroll
    for (int i = 0; i < CH; ++i) sum += loc[i];
    s[t] = sum;
    __syncthreads();
    for (int off = 1; off < 1024; off <<= 1) {
        int v = (t >= off) ? s[t - off] : 0;
        __syncthreads();
        s[t] += v;
        __syncthreads();
    }
    int run = s[t] - sum;
#pragma unroll
    for (int i = 0; i < CH; ++i) {
        int idx = base + i;
        if (idx < N_NODES) {
            rowptr[idx] = run;
            cursor[idx] = run;
            run += loc[i];
        }
    }
    if (t == 1023) rowptr[N_NODES] = s[1023];
}

// CSR fill; also records csrdst so k_edgew is CSR-ordered.
__global__ __launch_bounds__(256) void k_fill(const int* __restrict__ src,
                                              const int* __restrict__ dst,
                                              int* __restrict__ cursor,
                                              int* __restrict__ csr_src,
                                              int* __restrict__ csr_dst) {
    int i = blockIdx.x * 256 + threadIdx.x;
    if (i < N_EDGES) {
        int d = dst[i];
        int pos = atomicAdd(&cursor[d], 1);
        csr_src[pos] = src[i];
        csr_dst[pos] = d;
    }
}

// ---------------- GEMM: persistent waves, 5 tiles/wave, software-pipelined ----------------
// Grid 1875 blocks x 4 waves = 7500 waves; ROW_TILES/7500 = exactly 5 tiles per wave.
// Per iteration: issue NEXT tile's 4 A-loads first (latency hides under current
// tile's MFMA + LDS transpose + full-line stores). dl/dr accessed only with
// compile-time indices (rule #20: runtime ext_vector index -> scratch).
// Epilogue: acc -> LDS [16][72] (padded) -> bf16x8 full-line global stores.
__global__ __launch_bounds__(256) void k_gemm(
    const float* __restrict__ h,
    const bf16_t* __restrict__ wfb,
    const bf16_t* __restrict__ wrb,
    const bf16_t* __restrict__ ulb,
    const bf16_t* __restrict__ urb,
    bf16_t* __restrict__ ft,
    bf16_t* __restrict__ resb,
    float* __restrict__ al,
    float* __restrict__ ar)
{
    __shared__ bf16_t sb[4][2][16 * 72];
    int wv   = threadIdx.x >> 6;
    int lane = threadIdx.x & 63;
    int lr = lane & 15, lg = lane >> 4;
    int l8 = lane & 7,  lrow = lane >> 3;
    bf16_t* fs = &sb[wv][0][0];
    bf16_t* rs = &sb[wv][1][0];

    const f32x4*  hv  = reinterpret_cast<const f32x4*>(h);
    const bf16x8* wf  = reinterpret_cast<const bf16x8*>(wfb);
    const bf16x8* wr  = reinterpret_cast<const bf16x8*>(wrb);
    const bf16x8* ulv = reinterpret_cast<const bf16x8*>(ulb);
    const bf16x8* urv = reinterpret_cast<const bf16x8*>(urb);
    bf16x8 ul0 = ulv[lr * 8 + lg], ul1 = ulv[lr * 8 + 4 + lg];
    bf16x8 ur0 = urv[lr * 8 + lg], ur1 = urv[lr * 8 + 4 + lg];

    const int nw = 1875 * 4;                    // total waves
    int tile = blockIdx.x * 4 + wv;

    f32x4 c0, c1, c2, c3;
    if (tile < ROW_TILES) {
        int ab = (tile * 16 + lr) * 16 + lg * 2;
        c0 = hv[ab];     c1 = hv[ab + 1];
        c2 = hv[ab + 8]; c3 = hv[ab + 9];
    }
    while (tile < ROW_TILES) {
        int nxt = tile + nw;
        f32x4 n0, n1, n2, n3;
        if (nxt < ROW_TILES) {                  // prefetch next tile's A
            int ab = (nxt * 16 + lr) * 16 + lg * 2;
            n0 = hv[ab];     n1 = hv[ab + 1];
            n2 = hv[ab + 8]; n3 = hv[ab + 9];
        }
        bf16x8 a0 = cvt8(c0, c1), a1 = cvt8(c2, c3);
        int r0 = tile << 4;
        int r  = r0 + lr;
        int hh = r % NHEAD;

        // attn dots via MFMA: D[head][node]; static-index extraction only
        f32x4 dl = {0.f, 0.f, 0.f, 0.f}, dr = {0.f, 0.f, 0.f, 0.f};
        dl = __builtin_amdgcn_mfma_f32_16x16x32_bf16(ul0, a0, dl, 0, 0, 0);
        dl = __builtin_amdgcn_mfma_f32_16x16x32_bf16(ul1, a1, dl, 0, 0, 0);
        dr = __builtin_amdgcn_mfma_f32_16x16x32_bf16(ur0, a0, dr, 0, 0, 0);
        dr = __builtin_amdgcn_mfma_f32_16x16x32_bf16(ur1, a1, dr, 0, 0, 0);
        if (lg == (hh >> 2)) {
#pragma unroll
            for (int j = 0; j < 4; ++j)
                if ((hh & 3) == j) { al[r] = dl[j]; ar[r] = dr[j]; }
        }

        // main GEMMs -> LDS (padded stride 72 kills the 16-way write conflict)
#pragma unroll
        for (int nt = 0; nt < 4; ++nt) {
            int brow = (nt * 16 + lr) * 8;
            f32x4 z = {0.f, 0.f, 0.f, 0.f};
            z = __builtin_amdgcn_mfma_f32_16x16x32_bf16(wf[brow + lg],     a0, z, 0, 0, 0);
            z = __builtin_amdgcn_mfma_f32_16x16x32_bf16(wf[brow + 4 + lg], a1, z, 0, 0, 0);
            f32x4 y = {0.f, 0.f, 0.f, 0.f};
            y = __builtin_amdgcn_mfma_f32_16x16x32_bf16(wr[brow + lg],     a0, y, 0, 0, 0);
            y = __builtin_amdgcn_mfma_f32_16x16x32_bf16(wr[brow + 4 + lg], a1, y, 0, 0, 0);
            bf16x4 pf, pe;
#pragma unroll
            for (int j = 0; j < 4; ++j) { pf[j] = (bf16_t)z[j]; pe[j] = (bf16_t)y[j]; }
            *reinterpret_cast<bf16x4*>(fs + lr * 72 + nt * 16 + lg * 4) = pf;
            *reinterpret_cast<bf16x4*>(rs + lr * 72 + nt * 16 + lg * 4) = pe;
        }

        // LDS -> full-line stores: lane l8 owns 16 contiguous bytes of row lrow(+8k)
#pragma unroll
        for (int k = 0; k < 2; ++k) {
            int row = lrow + k * 8;
            bf16x8 vf = *reinterpret_cast<const bf16x8*>(fs + row * 72 + l8 * 8);
            bf16x8 vr = *reinterpret_cast<const bf16x8*>(rs + row * 72 + l8 * 8);
            *reinterpret_cast<bf16x8*>(ft   + (r0 + row) * 64 + l8 * 8) = vf;
            *reinterpret_cast<bf16x8*>(resb + (r0 + row) * 64 + l8 * 8) = vr;
        }

        c0 = n0; c1 = n1; c2 = n2; c3 = n3;
        tile = nxt;
    }
}

// ---------------- per-edge softmax weights, all 12 heads, EDGE-major [E][12] ----------------
__global__ __launch_bounds__(256) void k_edgew(
    const int* __restrict__ csr_src, const int* __restrict__ csr_dst,
    const float* __restrict__ al, const float* __restrict__ ar,
    float* __restrict__ w)
{
    int e = blockIdx.x * 256 + threadIdx.x;
    if (e >= N_EDGES) return;
    int s = csr_src[e], d = csr_dst[e];
    const f32x4* ap = reinterpret_cast<const f32x4*>(al + s * NHEAD);
    const f32x4* bp = reinterpret_cast<const f32x4*>(ar + d * NHEAD);
    f32x4* wp = reinterpret_cast<f32x4*>(w + e * NHEAD);
#pragma unroll
    for (int q = 0; q < 3; ++q) {
        f32x4 a = ap[q], b = bp[q];
        f32x4 o;
#pragma unroll
        for (int j = 0; j < 4; ++j) {
            float x = a[j] + b[j];
            x = (x > 0.f) ? x : 0.2f * x;          // leaky_relu
            o[j] = __expf(x);
        }
        wp[q] = o;
    }
}

// ---------------- softmax-normalize + aggregate + residual + relu ----------------
// ONE WAVE PER DST NODE, all 12 heads; per edge two fat requests (1024B+512B).
#define DB 4
__global__ __launch_bounds__(256) void k_agg(
    const int* __restrict__ rowptr, const int* __restrict__ csr_src,
    const float* __restrict__ w,
    const bf16_t* __restrict__ ft, const bf16_t* __restrict__ resb,
    float* __restrict__ out)
{
    int d0 = (blockIdx.x * 256 + threadIdx.x) >> 6;
    if (d0 >= N_NODES) return;
    int l  = threadIdx.x & 63;
    int hA = l >> 3;
    int hB = 8 + (l >> 4);
    int beg = rowptr[d0], end = rowptr[d0 + 1];

    float accA[8] = {0,0,0,0,0,0,0,0};
    float accB[4] = {0,0,0,0};
    float denA = 0.f, denB = 0.f;

    for (int j0 = beg; j0 < end; j0 += DB) {
        int idx[DB]; float wA[DB], wB[DB];
        bf16x8 vA[DB]; bf16x4 vB[DB];
#pragma unroll
        for (int u = 0; u < DB; ++u) {
            int j = j0 + u;
            bool ok = j < end;                 // wave-uniform
            idx[u] = csr_src[ok ? j : beg];
            wA[u] = ok ? w[j * NHEAD + hA] : 0.f;
            wB[u] = ok ? w[j * NHEAD + hB] : 0.f;
        }
#pragma unroll
        for (int u = 0; u < DB; ++u) {
            const bf16_t* row = ft + idx[u] * 768;
            vA[u] = *reinterpret_cast<const bf16x8*>(row + 8 * l);
            vB[u] = *reinterpret_cast<const bf16x4*>(row + 512 + 4 * l);
        }
#pragma unroll
        for (int u = 0; u < DB; ++u) {
            denA += wA[u]; denB += wB[u];
#pragma unroll
            for (int k = 0; k < 8; ++k) accA[k] += wA[u] * (float)vA[u][k];
#pragma unroll
            for (int k = 0; k < 4; ++k) accB[k] += wB[u] * (float)vB[u][k];
        }
    }

    const bf16_t* rrow = resb + d0 * 768;
    bf16x8 rA = *reinterpret_cast<const bf16x8*>(rrow + 8 * l);
    bf16x4 rB = *reinterpret_cast<const bf16x4*>(rrow + 512 + 4 * l);
    float* orow = out + d0 * 768;
    f32x4 o0, o1, o2;
    float ia = 1.f / denA, ib = 1.f / denB;
#pragma unroll
    for (int k = 0; k < 4; ++k) {
        float x = (float)rA[k] + accA[k] * ia;         o0[k] = x > 0.f ? x : 0.f;
        float y = (float)rA[k + 4] + accA[k + 4] * ia; o1[k] = y > 0.f ? y : 0.f;
        float z = (float)rB[k] + accB[k] * ib;         o2[k] = z > 0.f ? z : 0.f;
    }
    __builtin_nontemporal_store(o0, reinterpret_cast<f32x4*>(orow + 8 * l));
    __builtin_nontemporal_store(o1, reinterpret_cast<f32x4*>(orow + 8 * l + 4));
    __builtin_nontemporal_store(o2, reinterpret_cast<f32x4*>(orow + 512 + 4 * l));
}

extern "C" void kernel_launch(void* const* d_in, const int* in_sizes, int n_in,
                              void* d_out, int out_size, void* d_ws, size_t ws_size,
                              hipStream_t stream) {
    const float* h    = (const float*)d_in[0];
    const float* wfc  = (const float*)d_in[1];
    const float* attl = (const float*)d_in[2];
    const float* attr = (const float*)d_in[3];
    const float* wres = (const float*)d_in[4];
    const int*   src  = (const int*)d_in[5];
    const int*   dst  = (const int*)d_in[6];
    float* out = (float*)d_out;

    char* ws = (char*)d_ws;
    bf16_t* ft     = (bf16_t*)(ws + 0);          //  76,800,000 B
    bf16_t* resb   = (bf16_t*)(ws + 76800000);   //  76,800,000 B
    float*  al     = (float*)(ws + 153600000);   //   2,400,000 B
    float*  ar     = (float*)(ws + 156000000);   //   2,400,000 B
    int*    deg    = (int*)(ws + 158400000);     //     200,448 B
    int*    rowptr = (int*)(ws + 158600448);     //     200,448 B
    int*    cursor = (int*)(ws + 158800896);     //     200,448 B
    int*    csrsrc = (int*)(ws + 159001344);     //   1,000,000 B
    int*    csrdst = (int*)(ws + 160001344);     //   1,000,000 B
    bf16_t* wfb    = (bf16_t*)(ws + 161001344);  //       8,192 B
    bf16_t* wrb    = (bf16_t*)(ws + 161009536);  //       8,192 B
    float*  wbuf   = (float*)(ws + 161017728);   //  12,000,000 B
    bf16_t* ulb    = (bf16_t*)(ws + 173017728);  //       2,048 B
    bf16_t* urb    = (bf16_t*)(ws + 173019776);  //       2,048 B (end ~173.02 MB)

    (void)hipMemsetAsync(deg, 0, N_NODES * sizeof(int), stream);
    k_deg_prep<<<1001, 256, 0, stream>>>(dst, deg, wfc, wres, attl, attr, wfb, wrb, ulb, urb);
    k_scan<<<1, 1024, 0, stream>>>(deg, rowptr, cursor);
    k_fill<<<977, 256, 0, stream>>>(src, dst, cursor, csrsrc, csrdst);
    k_gemm<<<1875, 256, 0, stream>>>(h, wfb, wrb, ulb, urb, ft, resb, al, ar);
    k_edgew<<<977, 256, 0, stream>>>(csrsrc, csrdst, al, ar, wbuf);
    k_agg<<<(N_NODES + 3) / 4, 256, 0, stream>>>(rowptr, csrsrc, wbuf, ft, resb, out);
}

// Round 11
// 239.068 us; speedup vs baseline: 2.2092x; 1.0417x over previous
//
#include <hip/hip_runtime.h>
#include <hip/hip_bf16.h>

#define N_NODES 50000
#define N_EDGES 250000
#define NHEAD   12
#define NH      (N_NODES * NHEAD)   /* 600000 rows of 64 */
#define ROW_TILES (NH / 16)         /* 37500 */

typedef __bf16 bf16_t;
typedef __bf16 bf16x8 __attribute__((ext_vector_type(8)));
typedef __bf16 bf16x4 __attribute__((ext_vector_type(4)));
typedef float  f32x4  __attribute__((ext_vector_type(4)));

__device__ __forceinline__ bf16x8 cvt8(f32x4 a, f32x4 b) {
    bf16x8 r;
    r[0] = (bf16_t)a[0]; r[1] = (bf16_t)a[1]; r[2] = (bf16_t)a[2]; r[3] = (bf16_t)a[3];
    r[4] = (bf16_t)b[0]; r[5] = (bf16_t)b[1]; r[6] = (bf16_t)b[2]; r[7] = (bf16_t)b[3];
    return r;
}

// ---------------- prep: degree histogram, weight cvt, ul/ur = W^T.att tables ----------------
// ul[h][d] = sum_e attl[h][e]*Wfc[e][d]; ur[h][d] = sum_e attr[h][e]*Wfc[e][d].
// Tables stored [16][64] bf16, rows 12..15 zeroed (MFMA pad).
__global__ __launch_bounds__(256) void k_deg_prep(
    const int* __restrict__ dst, int* __restrict__ deg,
    const float* __restrict__ wfc, const float* __restrict__ wres,
    const float* __restrict__ attl, const float* __restrict__ attr,
    bf16_t* __restrict__ wfb, bf16_t* __restrict__ wrb,
    bf16_t* __restrict__ ulb, bf16_t* __restrict__ urb)
{
    int b = blockIdx.x;
    if (b < 977) {
        int i = b * 256 + threadIdx.x;
        if (i < N_EDGES) atomicAdd(&deg[dst[i]], 1);
    } else if (b < 993) {
        int t = (b - 977) * 256 + threadIdx.x;   // 0..4095
        wfb[t] = (bf16_t)wfc[t];
        wrb[t] = (bf16_t)wres[t];
    } else if (b < 997) {
        int u = (b - 993) * 256 + threadIdx.x;   // 0..1023
        int hh = u >> 6, d = u & 63;
        float s = 0.f;
        if (hh < NHEAD) {
#pragma unroll 8
            for (int e = 0; e < 64; ++e) s += attl[hh * 64 + e] * wfc[e * 64 + d];
        }
        ulb[u] = (bf16_t)s;
    } else {
        int u = (b - 997) * 256 + threadIdx.x;   // 0..1023
        int hh = u >> 6, d = u & 63;
        float s = 0.f;
        if (hh < NHEAD) {
#pragma unroll 8
            for (int e = 0; e < 64; ++e) s += attr[hh * 64 + e] * wfc[e * 64 + d];
        }
        urb[u] = (bf16_t)s;
    }
}

// single block, 1024 threads, 52 nodes/thread; int4-vectorized loads.
__global__ __launch_bounds__(1024) void k_scan(const int* __restrict__ deg,
                                               int* __restrict__ rowptr,
                                               int* __restrict__ cursor) {
    __shared__ int s[1024];
    const int CH = 52;
    int t = threadIdx.x;
    int base = t * CH;
    int loc[CH];
    if (base + CH <= N_NODES) {
        const int4* p = reinterpret_cast<const int4*>(deg + base);
#pragma unroll
        for (int i = 0; i < CH / 4; ++i) {
            int4 q = p[i];
            loc[4 * i + 0] = q.x; loc[4 * i + 1] = q.y;
            loc[4 * i + 2] = q.z; loc[4 * i + 3] = q.w;
        }
    } else {
#pragma unroll
        for (int i = 0; i < CH; ++i) {
            int idx = base + i;
            loc[i] = (idx < N_NODES) ? deg[idx] : 0;
        }
    }
    int sum = 0;
#pragma unroll
    for (int i = 0; i < CH; ++i) sum += loc[i];
    s[t] = sum;
    __syncthreads();
    for (int off = 1; off < 1024; off <<= 1) {
        int v = (t >= off) ? s[t - off] : 0;
        __syncthreads();
        s[t] += v;
        __syncthreads();
    }
    int run = s[t] - sum;
#pragma unroll
    for (int i = 0; i < CH; ++i) {
        int idx = base + i;
        if (idx < N_NODES) {
            rowptr[idx] = run;
            cursor[idx] = run;
            run += loc[i];
        }
    }
    if (t == 1023) rowptr[N_NODES] = s[1023];
}

// ---------------- fused CSR-fill + persistent GEMM ----------------
// Blocks 0..976: CSR fill (latency-bound atomics) — hides under the GEMM.
// Blocks 977..2851: persistent GEMM, 1875x4 waves, exactly 5 tiles/wave,
// next-tile A-loads prefetched before current-tile compute. dl/dr accessed
// only with compile-time indices. Epilogue: acc -> padded LDS [16][72] ->
// full-line bf16x8 global stores.
__global__ __launch_bounds__(256) void k_fill_gemm(
    const int* __restrict__ src, const int* __restrict__ dst,
    int* __restrict__ cursor, int* __restrict__ csr_src,
    const float* __restrict__ h,
    const bf16_t* __restrict__ wfb,
    const bf16_t* __restrict__ wrb,
    const bf16_t* __restrict__ ulb,
    const bf16_t* __restrict__ urb,
    bf16_t* __restrict__ ft,
    bf16_t* __restrict__ resb,
    float* __restrict__ al,
    float* __restrict__ ar)
{
    __shared__ bf16_t sb[4][2][16 * 72];
    if (blockIdx.x < 977) {
        int i = blockIdx.x * 256 + threadIdx.x;
        if (i < N_EDGES) {
            int d = dst[i];
            int pos = atomicAdd(&cursor[d], 1);
            csr_src[pos] = src[i];
        }
        return;
    }
    int bid  = blockIdx.x - 977;
    int wv   = threadIdx.x >> 6;
    int lane = threadIdx.x & 63;
    int lr = lane & 15, lg = lane >> 4;
    int l8 = lane & 7,  lrow = lane >> 3;
    bf16_t* fs = &sb[wv][0][0];
    bf16_t* rs = &sb[wv][1][0];

    const f32x4*  hv  = reinterpret_cast<const f32x4*>(h);
    const bf16x8* wf  = reinterpret_cast<const bf16x8*>(wfb);
    const bf16x8* wr  = reinterpret_cast<const bf16x8*>(wrb);
    const bf16x8* ulv = reinterpret_cast<const bf16x8*>(ulb);
    const bf16x8* urv = reinterpret_cast<const bf16x8*>(urb);
    bf16x8 ul0 = ulv[lr * 8 + lg], ul1 = ulv[lr * 8 + 4 + lg];
    bf16x8 ur0 = urv[lr * 8 + lg], ur1 = urv[lr * 8 + 4 + lg];

    const int nw = 1875 * 4;                    // total gemm waves
    int tile = bid * 4 + wv;

    f32x4 c0, c1, c2, c3;
    if (tile < ROW_TILES) {
        int ab = (tile * 16 + lr) * 16 + lg * 2;
        c0 = hv[ab];     c1 = hv[ab + 1];
        c2 = hv[ab + 8]; c3 = hv[ab + 9];
    }
    while (tile < ROW_TILES) {
        int nxt = tile + nw;
        f32x4 n0, n1, n2, n3;
        if (nxt < ROW_TILES) {                  // prefetch next tile's A
            int ab = (nxt * 16 + lr) * 16 + lg * 2;
            n0 = hv[ab];     n1 = hv[ab + 1];
            n2 = hv[ab + 8]; n3 = hv[ab + 9];
        }
        bf16x8 a0 = cvt8(c0, c1), a1 = cvt8(c2, c3);
        int r0 = tile << 4;
        int r  = r0 + lr;
        int hh = r % NHEAD;

        // attn dots via MFMA: D[head][node]; static-index extraction only
        f32x4 dl = {0.f, 0.f, 0.f, 0.f}, dr = {0.f, 0.f, 0.f, 0.f};
        dl = __builtin_amdgcn_mfma_f32_16x16x32_bf16(ul0, a0, dl, 0, 0, 0);
        dl = __builtin_amdgcn_mfma_f32_16x16x32_bf16(ul1, a1, dl, 0, 0, 0);
        dr = __builtin_amdgcn_mfma_f32_16x16x32_bf16(ur0, a0, dr, 0, 0, 0);
        dr = __builtin_amdgcn_mfma_f32_16x16x32_bf16(ur1, a1, dr, 0, 0, 0);
        if (lg == (hh >> 2)) {
#pragma unroll
            for (int j = 0; j < 4; ++j)
                if ((hh & 3) == j) { al[r] = dl[j]; ar[r] = dr[j]; }
        }

        // main GEMMs -> LDS (padded stride 72 kills the write conflict)
#pragma unroll
        for (int nt = 0; nt < 4; ++nt) {
            int brow = (nt * 16 + lr) * 8;
            f32x4 z = {0.f, 0.f, 0.f, 0.f};
            z = __builtin_amdgcn_mfma_f32_16x16x32_bf16(wf[brow + lg],     a0, z, 0, 0, 0);
            z = __builtin_amdgcn_mfma_f32_16x16x32_bf16(wf[brow + 4 + lg], a1, z, 0, 0, 0);
            f32x4 y = {0.f, 0.f, 0.f, 0.f};
            y = __builtin_amdgcn_mfma_f32_16x16x32_bf16(wr[brow + lg],     a0, y, 0, 0, 0);
            y = __builtin_amdgcn_mfma_f32_16x16x32_bf16(wr[brow + 4 + lg], a1, y, 0, 0, 0);
            bf16x4 pf, pe;
#pragma unroll
            for (int j = 0; j < 4; ++j) { pf[j] = (bf16_t)z[j]; pe[j] = (bf16_t)y[j]; }
            *reinterpret_cast<bf16x4*>(fs + lr * 72 + nt * 16 + lg * 4) = pf;
            *reinterpret_cast<bf16x4*>(rs + lr * 72 + nt * 16 + lg * 4) = pe;
        }

        // LDS -> full-line stores: lane l8 owns 16 contiguous bytes of row lrow(+8k)
#pragma unroll
        for (int k = 0; k < 2; ++k) {
            int row = lrow + k * 8;
            bf16x8 vf = *reinterpret_cast<const bf16x8*>(fs + row * 72 + l8 * 8);
            bf16x8 vr = *reinterpret_cast<const bf16x8*>(rs + row * 72 + l8 * 8);
            *reinterpret_cast<bf16x8*>(ft   + (r0 + row) * 64 + l8 * 8) = vf;
            *reinterpret_cast<bf16x8*>(resb + (r0 + row) * 64 + l8 * 8) = vr;
        }

        c0 = n0; c1 = n1; c2 = n2; c3 = n3;
        tile = nxt;
    }
}

// ---------------- fused edge-softmax + aggregate + residual + relu ----------------
// ONE WAVE PER DST NODE, all 12 heads; per edge two fat ft requests
// (1024B+512B). Softmax weights computed IN-KERNEL: al[s*12+h] is a 48B
// L2-resident gather (table 2.4MB), ar[d] loaded once per wave; exp on the
// VALU (was: separate k_edgew pass + 24MB of wbuf traffic).
// Lane l owns: part A = head l>>3, feats (l&7)*8..+7 ; part B = head
// 8+(l>>4), feats (l&15)*4..+3.
#define DB 4
__global__ __launch_bounds__(256) void k_agg(
    const int* __restrict__ rowptr, const int* __restrict__ csr_src,
    const float* __restrict__ al, const float* __restrict__ ar,
    const bf16_t* __restrict__ ft, const bf16_t* __restrict__ resb,
    float* __restrict__ out)
{
    int d0 = (blockIdx.x * 256 + threadIdx.x) >> 6;
    if (d0 >= N_NODES) return;
    int l  = threadIdx.x & 63;
    int hA = l >> 3;
    int hB = 8 + (l >> 4);
    int beg = rowptr[d0], end = rowptr[d0 + 1];
    float arA = ar[d0 * NHEAD + hA];
    float arB = ar[d0 * NHEAD + hB];

    float accA[8] = {0,0,0,0,0,0,0,0};
    float accB[4] = {0,0,0,0};
    float denA = 0.f, denB = 0.f;

    for (int j0 = beg; j0 < end; j0 += DB) {
        int idx[DB]; float wA[DB], wB[DB];
        bf16x8 vA[DB]; bf16x4 vB[DB];
#pragma unroll
        for (int u = 0; u < DB; ++u) {
            int j = j0 + u;
            idx[u] = csr_src[(j < end) ? j : beg];
        }
#pragma unroll
        for (int u = 0; u < DB; ++u) {
            float xa = al[idx[u] * NHEAD + hA] + arA;
            float xb = al[idx[u] * NHEAD + hB] + arB;
            xa = (xa > 0.f) ? xa : 0.2f * xa;      // leaky_relu
            xb = (xb > 0.f) ? xb : 0.2f * xb;
            bool ok = (j0 + u) < end;              // wave-uniform
            wA[u] = ok ? __expf(xa) : 0.f;
            wB[u] = ok ? __expf(xb) : 0.f;
        }
#pragma unroll
        for (int u = 0; u < DB; ++u) {
            const bf16_t* row = ft + idx[u] * 768;
            vA[u] = *reinterpret_cast<const bf16x8*>(row + 8 * l);
            vB[u] = *reinterpret_cast<const bf16x4*>(row + 512 + 4 * l);
        }
#pragma unroll
        for (int u = 0; u < DB; ++u) {
            denA += wA[u]; denB += wB[u];
#pragma unroll
            for (int k = 0; k < 8; ++k) accA[k] += wA[u] * (float)vA[u][k];
#pragma unroll
            for (int k = 0; k < 4; ++k) accB[k] += wB[u] * (float)vB[u][k];
        }
    }

    const bf16_t* rrow = resb + d0 * 768;
    bf16x8 rA = *reinterpret_cast<const bf16x8*>(rrow + 8 * l);
    bf16x4 rB = *reinterpret_cast<const bf16x4*>(rrow + 512 + 4 * l);
    float* orow = out + d0 * 768;
    f32x4 o0, o1, o2;
    float ia = 1.f / denA, ib = 1.f / denB;
#pragma unroll
    for (int k = 0; k < 4; ++k) {
        float x = (float)rA[k] + accA[k] * ia;         o0[k] = x > 0.f ? x : 0.f;
        float y = (float)rA[k + 4] + accA[k + 4] * ia; o1[k] = y > 0.f ? y : 0.f;
        float z = (float)rB[k] + accB[k] * ib;         o2[k] = z > 0.f ? z : 0.f;
    }
    __builtin_nontemporal_store(o0, reinterpret_cast<f32x4*>(orow + 8 * l));
    __builtin_nontemporal_store(o1, reinterpret_cast<f32x4*>(orow + 8 * l + 4));
    __builtin_nontemporal_store(o2, reinterpret_cast<f32x4*>(orow + 512 + 4 * l));
}

extern "C" void kernel_launch(void* const* d_in, const int* in_sizes, int n_in,
                              void* d_out, int out_size, void* d_ws, size_t ws_size,
                              hipStream_t stream) {
    const float* h    = (const float*)d_in[0];
    const float* wfc  = (const float*)d_in[1];
    const float* attl = (const float*)d_in[2];
    const float* attr = (const float*)d_in[3];
    const float* wres = (const float*)d_in[4];
    const int*   src  = (const int*)d_in[5];
    const int*   dst  = (const int*)d_in[6];
    float* out = (float*)d_out;

    char* ws = (char*)d_ws;
    bf16_t* ft     = (bf16_t*)(ws + 0);          //  76,800,000 B
    bf16_t* resb   = (bf16_t*)(ws + 76800000);   //  76,800,000 B
    float*  al     = (float*)(ws + 153600000);   //   2,400,000 B
    float*  ar     = (float*)(ws + 156000000);   //   2,400,000 B
    int*    deg    = (int*)(ws + 158400000);     //     200,448 B
    int*    rowptr = (int*)(ws + 158600448);     //     200,448 B
    int*    cursor = (int*)(ws + 158800896);     //     200,448 B
    int*    csrsrc = (int*)(ws + 159001344);     //   1,000,000 B
    bf16_t* wfb    = (bf16_t*)(ws + 160001344);  //       8,192 B
    bf16_t* wrb    = (bf16_t*)(ws + 160009536);  //       8,192 B
    bf16_t* ulb    = (bf16_t*)(ws + 160017728);  //       2,048 B
    bf16_t* urb    = (bf16_t*)(ws + 160019776);  //       2,048 B (end ~160 MB)

    (void)hipMemsetAsync(deg, 0, N_NODES * sizeof(int), stream);
    k_deg_prep<<<1001, 256, 0, stream>>>(dst, deg, wfc, wres, attl, attr, wfb, wrb, ulb, urb);
    k_scan<<<1, 1024, 0, stream>>>(deg, rowptr, cursor);
    k_fill_gemm<<<977 + 1875, 256, 0, stream>>>(src, dst, cursor, csrsrc,
                                                h, wfb, wrb, ulb, urb, ft, resb, al, ar);
    k_agg<<<(N_NODES + 3) / 4, 256, 0, stream>>>(rowptr, csrsrc, al, ar, ft, resb, out);
}

// Round 12
// 237.985 us; speedup vs baseline: 2.2193x; 1.0046x over previous
//
#include <hip/hip_runtime.h>
#include <hip/hip_bf16.h>

#define N_NODES 50000
#define N_EDGES 250000
#define NHEAD   12
#define NH      (N_NODES * NHEAD)   /* 600000 rows of 64 */
#define ROW_TILES (NH / 16)         /* 37500 */

typedef __bf16 bf16_t;
typedef __bf16 bf16x8 __attribute__((ext_vector_type(8)));
typedef __bf16 bf16x4 __attribute__((ext_vector_type(4)));
typedef float  f32x4  __attribute__((ext_vector_type(4)));

__device__ __forceinline__ bf16x8 cvt8(f32x4 a, f32x4 b) {
    bf16x8 r;
    r[0] = (bf16_t)a[0]; r[1] = (bf16_t)a[1]; r[2] = (bf16_t)a[2]; r[3] = (bf16_t)a[3];
    r[4] = (bf16_t)b[0]; r[5] = (bf16_t)b[1]; r[6] = (bf16_t)b[2]; r[7] = (bf16_t)b[3];
    return r;
}

// ---------------- prep: degree histogram (int4 edge reads), weight cvt, ul/ur ----------------
// b<245: 4 edges/thread histogram; b<261: wfc/wres->bf16; b<265: ul; b<269: ur.
// ul[h][d] = sum_e attl[h][e]*Wfc[e][d]; ur[h][d] = sum_e attr[h][e]*Wfc[e][d].
// Tables stored [16][64] bf16, rows 12..15 zeroed (MFMA pad).
__global__ __launch_bounds__(256) void k_deg_prep(
    const int* __restrict__ dst, int* __restrict__ deg,
    const float* __restrict__ wfc, const float* __restrict__ wres,
    const float* __restrict__ attl, const float* __restrict__ attr,
    bf16_t* __restrict__ wfb, bf16_t* __restrict__ wrb,
    bf16_t* __restrict__ ulb, bf16_t* __restrict__ urb)
{
    int b = blockIdx.x;
    if (b < 245) {
        int i4 = b * 256 + threadIdx.x;          // 62500 int4s = 250000 edges exactly
        if (i4 < N_EDGES / 4) {
            int4 q = reinterpret_cast<const int4*>(dst)[i4];
            atomicAdd(&deg[q.x], 1);
            atomicAdd(&deg[q.y], 1);
            atomicAdd(&deg[q.z], 1);
            atomicAdd(&deg[q.w], 1);
        }
    } else if (b < 261) {
        int t = (b - 245) * 256 + threadIdx.x;   // 0..4095
        wfb[t] = (bf16_t)wfc[t];
        wrb[t] = (bf16_t)wres[t];
    } else if (b < 265) {
        int u = (b - 261) * 256 + threadIdx.x;   // 0..1023
        int hh = u >> 6, d = u & 63;
        float s = 0.f;
        if (hh < NHEAD) {
#pragma unroll 8
            for (int e = 0; e < 64; ++e) s += attl[hh * 64 + e] * wfc[e * 64 + d];
        }
        ulb[u] = (bf16_t)s;
    } else {
        int u = (b - 265) * 256 + threadIdx.x;   // 0..1023
        int hh = u >> 6, d = u & 63;
        float s = 0.f;
        if (hh < NHEAD) {
#pragma unroll 8
            for (int e = 0; e < 64; ++e) s += attr[hh * 64 + e] * wfc[e * 64 + d];
        }
        urb[u] = (bf16_t)s;
    }
}

// single block, 1024 threads, 52 nodes/thread; int4-vectorized loads.
__global__ __launch_bounds__(1024) void k_scan(const int* __restrict__ deg,
                                               int* __restrict__ rowptr,
                                               int* __restrict__ cursor) {
    __shared__ int s[1024];
    const int CH = 52;
    int t = threadIdx.x;
    int base = t * CH;
    int loc[CH];
    if (base + CH <= N_NODES) {
        const int4* p = reinterpret_cast<const int4*>(deg + base);
#pragma unroll
        for (int i = 0; i < CH / 4; ++i) {
            int4 q = p[i];
            loc[4 * i + 0] = q.x; loc[4 * i + 1] = q.y;
            loc[4 * i + 2] = q.z; loc[4 * i + 3] = q.w;
        }
    } else {
#pragma unroll
        for (int i = 0; i < CH; ++i) {
            int idx = base + i;
            loc[i] = (idx < N_NODES) ? deg[idx] : 0;
        }
    }
    int sum = 0;
#pragma unroll
    for (int i = 0; i < CH; ++i) sum += loc[i];
    s[t] = sum;
    __syncthreads();
    for (int off = 1; off < 1024; off <<= 1) {
        int v = (t >= off) ? s[t - off] : 0;
        __syncthreads();
        s[t] += v;
        __syncthreads();
    }
    int run = s[t] - sum;
#pragma unroll
    for (int i = 0; i < CH; ++i) {
        int idx = base + i;
        if (idx < N_NODES) {
            rowptr[idx] = run;
            cursor[idx] = run;
            run += loc[i];
        }
    }
    if (t == 1023) rowptr[N_NODES] = s[1023];
}

// ---------------- fused CSR-fill + persistent GEMM ----------------
// Blocks 0..976: CSR fill (latency-bound atomics) — hides under the GEMM.
// Blocks 977..2851: persistent GEMM, 1875x4 waves, exactly 5 tiles/wave,
// next-tile A-loads prefetched before current-tile compute. dl/dr accessed
// only with compile-time indices. Epilogue: acc -> padded LDS [16][72] ->
// full-line bf16x8 global stores.
__global__ __launch_bounds__(256) void k_fill_gemm(
    const int* __restrict__ src, const int* __restrict__ dst,
    int* __restrict__ cursor, int* __restrict__ csr_src,
    const float* __restrict__ h,
    const bf16_t* __restrict__ wfb,
    const bf16_t* __restrict__ wrb,
    const bf16_t* __restrict__ ulb,
    const bf16_t* __restrict__ urb,
    bf16_t* __restrict__ ft,
    bf16_t* __restrict__ resb,
    float* __restrict__ al,
    float* __restrict__ ar)
{
    __shared__ bf16_t sb[4][2][16 * 72];
    if (blockIdx.x < 977) {
        int i = blockIdx.x * 256 + threadIdx.x;
        if (i < N_EDGES) {
            int d = dst[i];
            int pos = atomicAdd(&cursor[d], 1);
            csr_src[pos] = src[i];
        }
        return;
    }
    int bid  = blockIdx.x - 977;
    int wv   = threadIdx.x >> 6;
    int lane = threadIdx.x & 63;
    int lr = lane & 15, lg = lane >> 4;
    int l8 = lane & 7,  lrow = lane >> 3;
    bf16_t* fs = &sb[wv][0][0];
    bf16_t* rs = &sb[wv][1][0];

    const f32x4*  hv  = reinterpret_cast<const f32x4*>(h);
    const bf16x8* wf  = reinterpret_cast<const bf16x8*>(wfb);
    const bf16x8* wr  = reinterpret_cast<const bf16x8*>(wrb);
    const bf16x8* ulv = reinterpret_cast<const bf16x8*>(ulb);
    const bf16x8* urv = reinterpret_cast<const bf16x8*>(urb);
    bf16x8 ul0 = ulv[lr * 8 + lg], ul1 = ulv[lr * 8 + 4 + lg];
    bf16x8 ur0 = urv[lr * 8 + lg], ur1 = urv[lr * 8 + 4 + lg];

    const int nw = 1875 * 4;                    // total gemm waves
    int tile = bid * 4 + wv;

    f32x4 c0, c1, c2, c3;
    if (tile < ROW_TILES) {
        int ab = (tile * 16 + lr) * 16 + lg * 2;
        c0 = hv[ab];     c1 = hv[ab + 1];
        c2 = hv[ab + 8]; c3 = hv[ab + 9];
    }
    while (tile < ROW_TILES) {
        int nxt = tile + nw;
        f32x4 n0, n1, n2, n3;
        if (nxt < ROW_TILES) {                  // prefetch next tile's A
            int ab = (nxt * 16 + lr) * 16 + lg * 2;
            n0 = hv[ab];     n1 = hv[ab + 1];
            n2 = hv[ab + 8]; n3 = hv[ab + 9];
        }
        bf16x8 a0 = cvt8(c0, c1), a1 = cvt8(c2, c3);
        int r0 = tile << 4;
        int r  = r0 + lr;
        int hh = r % NHEAD;

        // attn dots via MFMA: D[head][node]; static-index extraction only
        f32x4 dl = {0.f, 0.f, 0.f, 0.f}, dr = {0.f, 0.f, 0.f, 0.f};
        dl = __builtin_amdgcn_mfma_f32_16x16x32_bf16(ul0, a0, dl, 0, 0, 0);
        dl = __builtin_amdgcn_mfma_f32_16x16x32_bf16(ul1, a1, dl, 0, 0, 0);
        dr = __builtin_amdgcn_mfma_f32_16x16x32_bf16(ur0, a0, dr, 0, 0, 0);
        dr = __builtin_amdgcn_mfma_f32_16x16x32_bf16(ur1, a1, dr, 0, 0, 0);
        if (lg == (hh >> 2)) {
#pragma unroll
            for (int j = 0; j < 4; ++j)
                if ((hh & 3) == j) { al[r] = dl[j]; ar[r] = dr[j]; }
        }

        // main GEMMs -> LDS (padded stride 72 kills the write conflict)
#pragma unroll
        for (int nt = 0; nt < 4; ++nt) {
            int brow = (nt * 16 + lr) * 8;
            f32x4 z = {0.f, 0.f, 0.f, 0.f};
            z = __builtin_amdgcn_mfma_f32_16x16x32_bf16(wf[brow + lg],     a0, z, 0, 0, 0);
            z = __builtin_amdgcn_mfma_f32_16x16x32_bf16(wf[brow + 4 + lg], a1, z, 0, 0, 0);
            f32x4 y = {0.f, 0.f, 0.f, 0.f};
            y = __builtin_amdgcn_mfma_f32_16x16x32_bf16(wr[brow + lg],     a0, y, 0, 0, 0);
            y = __builtin_amdgcn_mfma_f32_16x16x32_bf16(wr[brow + 4 + lg], a1, y, 0, 0, 0);
            bf16x4 pf, pe;
#pragma unroll
            for (int j = 0; j < 4; ++j) { pf[j] = (bf16_t)z[j]; pe[j] = (bf16_t)y[j]; }
            *reinterpret_cast<bf16x4*>(fs + lr * 72 + nt * 16 + lg * 4) = pf;
            *reinterpret_cast<bf16x4*>(rs + lr * 72 + nt * 16 + lg * 4) = pe;
        }

        // LDS -> full-line stores: lane l8 owns 16 contiguous bytes of row lrow(+8k)
#pragma unroll
        for (int k = 0; k < 2; ++k) {
            int row = lrow + k * 8;
            bf16x8 vf = *reinterpret_cast<const bf16x8*>(fs + row * 72 + l8 * 8);
            bf16x8 vr = *reinterpret_cast<const bf16x8*>(rs + row * 72 + l8 * 8);
            *reinterpret_cast<bf16x8*>(ft   + (r0 + row) * 64 + l8 * 8) = vf;
            *reinterpret_cast<bf16x8*>(resb + (r0 + row) * 64 + l8 * 8) = vr;
        }

        c0 = n0; c1 = n1; c2 = n2; c3 = n3;
        tile = nxt;
    }
}

// ---------------- fused edge-softmax + aggregate + residual + relu ----------------
// ONE WAVE PER DST NODE, all 12 heads. Request-count diet vs R11:
//  * readfirstlane(d0) -> rowptr/csr_src indexing is provably scalar -> SMEM
//    (s_load), zero VMEM slots for CSR walking.
//  * cooperative weights: lanes 0..47 each compute ONE (edge u=l/12, head
//    l%12) weight -> ONE 48-lane al-gather per 4-edge batch (was 8 per-lane
//    gathers), exp count /8; ds_bpermute (__shfl) distributes wA/wB.
//  Weight fp ops and fma order identical to R11 -> bit-identical output.
#define DB 4
__global__ __launch_bounds__(256) void k_agg(
    const int* __restrict__ rowptr, const int* __restrict__ csr_src,
    const float* __restrict__ al, const float* __restrict__ ar,
    const bf16_t* __restrict__ ft, const bf16_t* __restrict__ resb,
    float* __restrict__ out)
{
    int d0 = (blockIdx.x * 256 + threadIdx.x) >> 6;
    d0 = __builtin_amdgcn_readfirstlane(d0);
    if (d0 >= N_NODES) return;
    int l  = threadIdx.x & 63;
    int hA = l >> 3;              // part A: head l>>3, feats (l&7)*8..+7
    int hB = 8 + (l >> 4);        // part B: head 8+(l>>4), feats (l&15)*4..+3
    int u_l = l / 12;             // weight-compute mapping (lanes 0..47)
    int h_l = l - u_l * 12;
    int beg = rowptr[d0], end = rowptr[d0 + 1];          // s_load
    float arW = 0.f;
    if (l < 48) arW = ar[d0 * NHEAD + h_l];

    float accA[8] = {0,0,0,0,0,0,0,0};
    float accB[4] = {0,0,0,0};
    float denA = 0.f, denB = 0.f;

    for (int j0 = beg; j0 < end; j0 += DB) {
        int idx[DB];
#pragma unroll
        for (int u = 0; u < DB; ++u) {
            int j = j0 + u;
            idx[u] = csr_src[(j < end) ? j : beg];       // scalar (uniform addr)
        }
        // cooperative weight compute: one (edge,head) per lane, lanes 0..47
        float wv = 0.f;
        {
            int e = idx[0];
            e = (u_l == 1) ? idx[1] : e;
            e = (u_l == 2) ? idx[2] : e;
            e = (u_l == 3) ? idx[3] : e;
            if (l < 48) {
                float x = al[e * NHEAD + h_l] + arW;     // ONE gather instr/batch
                x = (x > 0.f) ? x : 0.2f * x;            // leaky_relu
                wv = ((j0 + u_l) < end) ? __expf(x) : 0.f;
            }
        }
        float wA[DB], wB[DB];
#pragma unroll
        for (int u = 0; u < DB; ++u) {
            wA[u] = __shfl(wv, u * 12 + hA, 64);
            wB[u] = __shfl(wv, u * 12 + hB, 64);
        }
        bf16x8 vA[DB]; bf16x4 vB[DB];
#pragma unroll
        for (int u = 0; u < DB; ++u) {
            const bf16_t* row = ft + idx[u] * 768;
            vA[u] = *reinterpret_cast<const bf16x8*>(row + 8 * l);
            vB[u] = *reinterpret_cast<const bf16x4*>(row + 512 + 4 * l);
        }
#pragma unroll
        for (int u = 0; u < DB; ++u) {
            denA += wA[u]; denB += wB[u];
#pragma unroll
            for (int k = 0; k < 8; ++k) accA[k] += wA[u] * (float)vA[u][k];
#pragma unroll
            for (int k = 0; k < 4; ++k) accB[k] += wB[u] * (float)vB[u][k];
        }
    }

    const bf16_t* rrow = resb + d0 * 768;
    bf16x8 rA = *reinterpret_cast<const bf16x8*>(rrow + 8 * l);
    bf16x4 rB = *reinterpret_cast<const bf16x4*>(rrow + 512 + 4 * l);
    float* orow = out + d0 * 768;
    f32x4 o0, o1, o2;
    float ia = 1.f / denA, ib = 1.f / denB;
#pragma unroll
    for (int k = 0; k < 4; ++k) {
        float x = (float)rA[k] + accA[k] * ia;         o0[k] = x > 0.f ? x : 0.f;
        float y = (float)rA[k + 4] + accA[k + 4] * ia; o1[k] = y > 0.f ? y : 0.f;
        float z = (float)rB[k] + accB[k] * ib;         o2[k] = z > 0.f ? z : 0.f;
    }
    __builtin_nontemporal_store(o0, reinterpret_cast<f32x4*>(orow + 8 * l));
    __builtin_nontemporal_store(o1, reinterpret_cast<f32x4*>(orow + 8 * l + 4));
    __builtin_nontemporal_store(o2, reinterpret_cast<f32x4*>(orow + 512 + 4 * l));
}

extern "C" void kernel_launch(void* const* d_in, const int* in_sizes, int n_in,
                              void* d_out, int out_size, void* d_ws, size_t ws_size,
                              hipStream_t stream) {
    const float* h    = (const float*)d_in[0];
    const float* wfc  = (const float*)d_in[1];
    const float* attl = (const float*)d_in[2];
    const float* attr = (const float*)d_in[3];
    const float* wres = (const float*)d_in[4];
    const int*   src  = (const int*)d_in[5];
    const int*   dst  = (const int*)d_in[6];
    float* out = (float*)d_out;

    char* ws = (char*)d_ws;
    bf16_t* ft     = (bf16_t*)(ws + 0);          //  76,800,000 B
    bf16_t* resb   = (bf16_t*)(ws + 76800000);   //  76,800,000 B
    float*  al     = (float*)(ws + 153600000);   //   2,400,000 B
    float*  ar     = (float*)(ws + 156000000);   //   2,400,000 B
    int*    deg    = (int*)(ws + 158400000);     //     200,448 B
    int*    rowptr = (int*)(ws + 158600448);     //     200,448 B
    int*    cursor = (int*)(ws + 158800896);     //     200,448 B
    int*    csrsrc = (int*)(ws + 159001344);     //   1,000,000 B
    bf16_t* wfb    = (bf16_t*)(ws + 160001344);  //       8,192 B
    bf16_t* wrb    = (bf16_t*)(ws + 160009536);  //       8,192 B
    bf16_t* ulb    = (bf16_t*)(ws + 160017728);  //       2,048 B
    bf16_t* urb    = (bf16_t*)(ws + 160019776);  //       2,048 B (end ~160 MB)

    (void)hipMemsetAsync(deg, 0, N_NODES * sizeof(int), stream);
    k_deg_prep<<<269, 256, 0, stream>>>(dst, deg, wfc, wres, attl, attr, wfb, wrb, ulb, urb);
    k_scan<<<1, 1024, 0, stream>>>(deg, rowptr, cursor);
    k_fill_gemm<<<977 + 1875, 256, 0, stream>>>(src, dst, cursor, csrsrc,
                                                h, wfb, wrb, ulb, urb, ft, resb, al, ar);
    k_agg<<<(N_NODES + 3) / 4, 256, 0, stream>>>(rowptr, csrsrc, al, ar, ft, resb, out);
}

// Round 13
// 209.744 us; speedup vs baseline: 2.5181x; 1.1346x over previous
//
#include <hip/hip_runtime.h>
#include <hip/hip_bf16.h>

#define N_NODES 50000
#define N_EDGES 250000
#define NHEAD   12
#define NH      (N_NODES * NHEAD)   /* 600000 rows of 64 */
#define ROW_TILES (NH / 16)         /* 37500 */

typedef __bf16 bf16_t;
typedef __bf16 bf16x8 __attribute__((ext_vector_type(8)));
typedef __bf16 bf16x4 __attribute__((ext_vector_type(4)));
typedef float  f32x4  __attribute__((ext_vector_type(4)));

__device__ __forceinline__ bf16x8 cvt8(f32x4 a, f32x4 b) {
    bf16x8 r;
    r[0] = (bf16_t)a[0]; r[1] = (bf16_t)a[1]; r[2] = (bf16_t)a[2]; r[3] = (bf16_t)a[3];
    r[4] = (bf16_t)b[0]; r[5] = (bf16_t)b[1]; r[6] = (bf16_t)b[2]; r[7] = (bf16_t)b[3];
    return r;
}

// ---------------- prep: degree histogram (int4 edge reads), weight cvt, ul/ur ----------------
__global__ __launch_bounds__(256) void k_deg_prep(
    const int* __restrict__ dst, int* __restrict__ deg,
    const float* __restrict__ wfc, const float* __restrict__ wres,
    const float* __restrict__ attl, const float* __restrict__ attr,
    bf16_t* __restrict__ wfb, bf16_t* __restrict__ wrb,
    bf16_t* __restrict__ ulb, bf16_t* __restrict__ urb)
{
    int b = blockIdx.x;
    if (b < 245) {
        int i4 = b * 256 + threadIdx.x;          // 62500 int4s = 250000 edges exactly
        if (i4 < N_EDGES / 4) {
            int4 q = reinterpret_cast<const int4*>(dst)[i4];
            atomicAdd(&deg[q.x], 1);
            atomicAdd(&deg[q.y], 1);
            atomicAdd(&deg[q.z], 1);
            atomicAdd(&deg[q.w], 1);
        }
    } else if (b < 261) {
        int t = (b - 245) * 256 + threadIdx.x;   // 0..4095
        wfb[t] = (bf16_t)wfc[t];
        wrb[t] = (bf16_t)wres[t];
    } else if (b < 265) {
        int u = (b - 261) * 256 + threadIdx.x;   // 0..1023
        int hh = u >> 6, d = u & 63;
        float s = 0.f;
        if (hh < NHEAD) {
#pragma unroll 8
            for (int e = 0; e < 64; ++e) s += attl[hh * 64 + e] * wfc[e * 64 + d];
        }
        ulb[u] = (bf16_t)s;
    } else {
        int u = (b - 265) * 256 + threadIdx.x;   // 0..1023
        int hh = u >> 6, d = u & 63;
        float s = 0.f;
        if (hh < NHEAD) {
#pragma unroll 8
            for (int e = 0; e < 64; ++e) s += attr[hh * 64 + e] * wfc[e * 64 + d];
        }
        urb[u] = (bf16_t)s;
    }
}

// single block, 1024 threads, 52 nodes/thread. Writes ONLY cursor (=segment
// starts); k_fill's atomics exhaust cursor into segment ENDs, so k_agg reads
// beg=cursor[d-1], end=cursor[d] post-fill — no rowptr array at all.
__global__ __launch_bounds__(1024) void k_scan(const int* __restrict__ deg,
                                               int* __restrict__ cursor) {
    __shared__ int s[1024];
    const int CH = 52;
    int t = threadIdx.x;
    int base = t * CH;
    int loc[CH];
    if (base + CH <= N_NODES) {
        const int4* p = reinterpret_cast<const int4*>(deg + base);
#pragma unroll
        for (int i = 0; i < CH / 4; ++i) {
            int4 q = p[i];
            loc[4 * i + 0] = q.x; loc[4 * i + 1] = q.y;
            loc[4 * i + 2] = q.z; loc[4 * i + 3] = q.w;
        }
    } else {
#pragma unroll
        for (int i = 0; i < CH; ++i) {
            int idx = base + i;
            loc[i] = (idx < N_NODES) ? deg[idx] : 0;
        }
    }
    int sum = 0;
#pragma unroll
    for (int i = 0; i < CH; ++i) sum += loc[i];
    s[t] = sum;
    __syncthreads();
    for (int off = 1; off < 1024; off <<= 1) {
        int v = (t >= off) ? s[t - off] : 0;
        __syncthreads();
        s[t] += v;
        __syncthreads();
    }
    int run = s[t] - sum;
#pragma unroll
    for (int i = 0; i < CH; ++i) {
        int idx = base + i;
        if (idx < N_NODES) {
            cursor[idx] = run;
            run += loc[i];
        }
    }
}

// ---------------- fused persistent GEMM + CSR-fill ----------------
// Blocks 0..1874: persistent GEMM (starts immediately); blocks 1875..2851:
// CSR fill (latency-bound atomics, slots in around the GEMM).
// h loads are NONTEMPORAL (single-use, 153.6MB): keeps ft/resb L3-resident
// for k_agg's gather (they fit: 153.6MB < 256MB L3).
__global__ __launch_bounds__(256) void k_fill_gemm(
    const int* __restrict__ src, const int* __restrict__ dst,
    int* __restrict__ cursor, int* __restrict__ csr_src,
    const float* __restrict__ h,
    const bf16_t* __restrict__ wfb,
    const bf16_t* __restrict__ wrb,
    const bf16_t* __restrict__ ulb,
    const bf16_t* __restrict__ urb,
    bf16_t* __restrict__ ft,
    bf16_t* __restrict__ resb,
    float* __restrict__ al,
    float* __restrict__ ar)
{
    __shared__ bf16_t sb[4][2][16 * 72];
    if (blockIdx.x >= 1875) {
        int i = (blockIdx.x - 1875) * 256 + threadIdx.x;
        if (i < N_EDGES) {
            int d = dst[i];
            int pos = atomicAdd(&cursor[d], 1);
            csr_src[pos] = src[i];
        }
        return;
    }
    int bid  = blockIdx.x;
    int wv   = threadIdx.x >> 6;
    int lane = threadIdx.x & 63;
    int lr = lane & 15, lg = lane >> 4;
    int l8 = lane & 7,  lrow = lane >> 3;
    bf16_t* fs = &sb[wv][0][0];
    bf16_t* rs = &sb[wv][1][0];

    const f32x4*  hv  = reinterpret_cast<const f32x4*>(h);
    const bf16x8* wf  = reinterpret_cast<const bf16x8*>(wfb);
    const bf16x8* wr  = reinterpret_cast<const bf16x8*>(wrb);
    const bf16x8* ulv = reinterpret_cast<const bf16x8*>(ulb);
    const bf16x8* urv = reinterpret_cast<const bf16x8*>(urb);
    bf16x8 ul0 = ulv[lr * 8 + lg], ul1 = ulv[lr * 8 + 4 + lg];
    bf16x8 ur0 = urv[lr * 8 + lg], ur1 = urv[lr * 8 + 4 + lg];

    const int nw = 1875 * 4;                    // total gemm waves
    int tile = bid * 4 + wv;

    f32x4 c0, c1, c2, c3;
    if (tile < ROW_TILES) {
        int ab = (tile * 16 + lr) * 16 + lg * 2;
        c0 = __builtin_nontemporal_load(hv + ab);
        c1 = __builtin_nontemporal_load(hv + ab + 1);
        c2 = __builtin_nontemporal_load(hv + ab + 8);
        c3 = __builtin_nontemporal_load(hv + ab + 9);
    }
    while (tile < ROW_TILES) {
        int nxt = tile + nw;
        f32x4 n0, n1, n2, n3;
        if (nxt < ROW_TILES) {                  // prefetch next tile's A (NT)
            int ab = (nxt * 16 + lr) * 16 + lg * 2;
            n0 = __builtin_nontemporal_load(hv + ab);
            n1 = __builtin_nontemporal_load(hv + ab + 1);
            n2 = __builtin_nontemporal_load(hv + ab + 8);
            n3 = __builtin_nontemporal_load(hv + ab + 9);
        }
        bf16x8 a0 = cvt8(c0, c1), a1 = cvt8(c2, c3);
        int r0 = tile << 4;
        int r  = r0 + lr;
        int hh = r % NHEAD;

        // attn dots via MFMA: D[head][node]; static-index extraction only
        f32x4 dl = {0.f, 0.f, 0.f, 0.f}, dr = {0.f, 0.f, 0.f, 0.f};
        dl = __builtin_amdgcn_mfma_f32_16x16x32_bf16(ul0, a0, dl, 0, 0, 0);
        dl = __builtin_amdgcn_mfma_f32_16x16x32_bf16(ul1, a1, dl, 0, 0, 0);
        dr = __builtin_amdgcn_mfma_f32_16x16x32_bf16(ur0, a0, dr, 0, 0, 0);
        dr = __builtin_amdgcn_mfma_f32_16x16x32_bf16(ur1, a1, dr, 0, 0, 0);
        if (lg == (hh >> 2)) {
#pragma unroll
            for (int j = 0; j < 4; ++j)
                if ((hh & 3) == j) { al[r] = dl[j]; ar[r] = dr[j]; }
        }

        // main GEMMs -> LDS (padded stride 72)
#pragma unroll
        for (int nt = 0; nt < 4; ++nt) {
            int brow = (nt * 16 + lr) * 8;
            f32x4 z = {0.f, 0.f, 0.f, 0.f};
            z = __builtin_amdgcn_mfma_f32_16x16x32_bf16(wf[brow + lg],     a0, z, 0, 0, 0);
            z = __builtin_amdgcn_mfma_f32_16x16x32_bf16(wf[brow + 4 + lg], a1, z, 0, 0, 0);
            f32x4 y = {0.f, 0.f, 0.f, 0.f};
            y = __builtin_amdgcn_mfma_f32_16x16x32_bf16(wr[brow + lg],     a0, y, 0, 0, 0);
            y = __builtin_amdgcn_mfma_f32_16x16x32_bf16(wr[brow + 4 + lg], a1, y, 0, 0, 0);
            bf16x4 pf, pe;
#pragma unroll
            for (int j = 0; j < 4; ++j) { pf[j] = (bf16_t)z[j]; pe[j] = (bf16_t)y[j]; }
            *reinterpret_cast<bf16x4*>(fs + lr * 72 + nt * 16 + lg * 4) = pf;
            *reinterpret_cast<bf16x4*>(rs + lr * 72 + nt * 16 + lg * 4) = pe;
        }

        // LDS -> full-line stores (cacheable: want ft/resb resident in L3)
#pragma unroll
        for (int k = 0; k < 2; ++k) {
            int row = lrow + k * 8;
            bf16x8 vf = *reinterpret_cast<const bf16x8*>(fs + row * 72 + l8 * 8);
            bf16x8 vr = *reinterpret_cast<const bf16x8*>(rs + row * 72 + l8 * 8);
            *reinterpret_cast<bf16x8*>(ft   + (r0 + row) * 64 + l8 * 8) = vf;
            *reinterpret_cast<bf16x8*>(resb + (r0 + row) * 64 + l8 * 8) = vr;
        }

        c0 = n0; c1 = n1; c2 = n2; c3 = n3;
        tile = nxt;
    }
}

// ---------------- fused edge-softmax + aggregate + residual + relu ----------------
// ONE WAVE PER DST NODE, all 12 heads; DB=8 edges in flight (16 fat ft loads).
// Segments: beg = cur[d0-1] (post-fill), end = cur[d0]. Cooperative weights:
// lane l<48 computes (edge l/12 and l/12+4, head l%12) -> 2 gather instrs per
// 8-edge batch; shfl distributes. resb read nontemporal (single-use).
#define DB 8
__global__ __launch_bounds__(256) void k_agg(
    const int* __restrict__ cur, const int* __restrict__ csr_src,
    const float* __restrict__ al, const float* __restrict__ ar,
    const bf16_t* __restrict__ ft, const bf16_t* __restrict__ resb,
    float* __restrict__ out)
{
    int d0 = (blockIdx.x * 256 + threadIdx.x) >> 6;
    d0 = __builtin_amdgcn_readfirstlane(d0);
    if (d0 >= N_NODES) return;
    int l  = threadIdx.x & 63;
    int hA = l >> 3;              // part A: head l>>3, feats (l&7)*8..+7
    int hB = 8 + (l >> 4);        // part B: head 8+(l>>4), feats (l&15)*4..+3
    int u_l = l / 12;             // weight lanes: l<48 -> edge pair (u_l, u_l+4)
    int h_l = l - u_l * 12;
    int beg = d0 ? cur[d0 - 1] : 0;                       // s_load
    int end = cur[d0];
    float arW = 0.f;
    if (l < 48) arW = ar[d0 * NHEAD + h_l];

    float accA[8] = {0,0,0,0,0,0,0,0};
    float accB[4] = {0,0,0,0};
    float denA = 0.f, denB = 0.f;

    for (int j0 = beg; j0 < end; j0 += DB) {
        int idx[DB];
#pragma unroll
        for (int u = 0; u < DB; ++u) {
            int j = j0 + u;
            idx[u] = csr_src[(j < end) ? j : beg];        // scalar (uniform addr)
        }
        // cooperative weights: lanes 0..47, two edges each
        float wv0 = 0.f, wv1 = 0.f;
        {
            int e0 = idx[0], e1 = idx[4];
            e0 = (u_l == 1) ? idx[1] : e0;  e1 = (u_l == 1) ? idx[5] : e1;
            e0 = (u_l == 2) ? idx[2] : e0;  e1 = (u_l == 2) ? idx[6] : e1;
            e0 = (u_l == 3) ? idx[3] : e0;  e1 = (u_l == 3) ? idx[7] : e1;
            if (l < 48) {
                float x0 = al[e0 * NHEAD + h_l] + arW;
                float x1 = al[e1 * NHEAD + h_l] + arW;
                x0 = (x0 > 0.f) ? x0 : 0.2f * x0;         // leaky_relu
                x1 = (x1 > 0.f) ? x1 : 0.2f * x1;
                wv0 = ((j0 + u_l)     < end) ? __expf(x0) : 0.f;
                wv1 = ((j0 + 4 + u_l) < end) ? __expf(x1) : 0.f;
            }
        }
        float wA[DB], wB[DB];
#pragma unroll
        for (int u = 0; u < 4; ++u) {
            wA[u]     = __shfl(wv0, u * 12 + hA, 64);
            wB[u]     = __shfl(wv0, u * 12 + hB, 64);
            wA[u + 4] = __shfl(wv1, u * 12 + hA, 64);
            wB[u + 4] = __shfl(wv1, u * 12 + hB, 64);
        }
        bf16x8 vA[DB]; bf16x4 vB[DB];
#pragma unroll
        for (int u = 0; u < DB; ++u) {
            const bf16_t* row = ft + idx[u] * 768;
            vA[u] = *reinterpret_cast<const bf16x8*>(row + 8 * l);
            vB[u] = *reinterpret_cast<const bf16x4*>(row + 512 + 4 * l);
        }
#pragma unroll
        for (int u = 0; u < DB; ++u) {
            denA += wA[u]; denB += wB[u];
#pragma unroll
            for (int k = 0; k < 8; ++k) accA[k] += wA[u] * (float)vA[u][k];
#pragma unroll
            for (int k = 0; k < 4; ++k) accB[k] += wB[u] * (float)vB[u][k];
        }
    }

    const bf16_t* rrow = resb + d0 * 768;
    bf16x8 rA = __builtin_nontemporal_load(reinterpret_cast<const bf16x8*>(rrow + 8 * l));
    bf16x4 rB = __builtin_nontemporal_load(reinterpret_cast<const bf16x4*>(rrow + 512 + 4 * l));
    float* orow = out + d0 * 768;
    f32x4 o0, o1, o2;
    float ia = 1.f / denA, ib = 1.f / denB;
#pragma unroll
    for (int k = 0; k < 4; ++k) {
        float x = (float)rA[k] + accA[k] * ia;         o0[k] = x > 0.f ? x : 0.f;
        float y = (float)rA[k + 4] + accA[k + 4] * ia; o1[k] = y > 0.f ? y : 0.f;
        float z = (float)rB[k] + accB[k] * ib;         o2[k] = z > 0.f ? z : 0.f;
    }
    __builtin_nontemporal_store(o0, reinterpret_cast<f32x4*>(orow + 8 * l));
    __builtin_nontemporal_store(o1, reinterpret_cast<f32x4*>(orow + 8 * l + 4));
    __builtin_nontemporal_store(o2, reinterpret_cast<f32x4*>(orow + 512 + 4 * l));
}

extern "C" void kernel_launch(void* const* d_in, const int* in_sizes, int n_in,
                              void* d_out, int out_size, void* d_ws, size_t ws_size,
                              hipStream_t stream) {
    const float* h    = (const float*)d_in[0];
    const float* wfc  = (const float*)d_in[1];
    const float* attl = (const float*)d_in[2];
    const float* attr = (const float*)d_in[3];
    const float* wres = (const float*)d_in[4];
    const int*   src  = (const int*)d_in[5];
    const int*   dst  = (const int*)d_in[6];
    float* out = (float*)d_out;

    char* ws = (char*)d_ws;
    bf16_t* ft     = (bf16_t*)(ws + 0);          //  76,800,000 B
    bf16_t* resb   = (bf16_t*)(ws + 76800000);   //  76,800,000 B
    float*  al     = (float*)(ws + 153600000);   //   2,400,000 B
    float*  ar     = (float*)(ws + 156000000);   //   2,400,000 B
    int*    deg    = (int*)(ws + 158400000);     //     200,448 B
    int*    cursor = (int*)(ws + 158800896);     //     200,448 B
    int*    csrsrc = (int*)(ws + 159001344);     //   1,000,000 B
    bf16_t* wfb    = (bf16_t*)(ws + 160001344);  //       8,192 B
    bf16_t* wrb    = (bf16_t*)(ws + 160009536);  //       8,192 B
    bf16_t* ulb    = (bf16_t*)(ws + 160017728);  //       2,048 B
    bf16_t* urb    = (bf16_t*)(ws + 160019776);  //       2,048 B (end ~160 MB)

    (void)hipMemsetAsync(deg, 0, N_NODES * sizeof(int), stream);
    k_deg_prep<<<269, 256, 0, stream>>>(dst, deg, wfc, wres, attl, attr, wfb, wrb, ulb, urb);
    k_scan<<<1, 1024, 0, stream>>>(deg, cursor);
    k_fill_gemm<<<1875 + 977, 256, 0, stream>>>(src, dst, cursor, csrsrc,
                                                h, wfb, wrb, ulb, urb, ft, resb, al, ar);
    k_agg<<<(N_NODES + 3) / 4, 256, 0, stream>>>(cursor, csrsrc, al, ar, ft, resb, out);
}